// Round 1
// baseline (3959.410 us; speedup 1.0000x reference)
//
#include <hip/hip_runtime.h>

// ============================================================================
// Persistent-kernel LSTM decoder for MI355X (gfx950).
// Design: one 256-block cooperative kernel; hand-rolled agent-scope grid
// barrier; bf16 MFMA (16x16x32) for all GEMMs with fp32 accumulate; fused
// gate pointwise + online (max,sumexp) softmax reduction (logits matrix is
// never materialized in memory).
// ============================================================================

typedef unsigned int uint;
typedef unsigned short ushort;
typedef __attribute__((ext_vector_type(8))) __bf16 bf16x8;
typedef __attribute__((ext_vector_type(4))) float f32x4;
typedef __attribute__((ext_vector_type(4))) ushort ushort4v;

// ---- problem dims ----
#define B_ 256
#define T_ 40
#define V_ 5000
#define D_ 512

// ---- workspace byte offsets (all 256-B aligned) ----
#define OFF_BAR 0L
#define OFF_W0 256L        // [2048][1152] bf16, row r = d*4+g
#define OFF_W1 4718848L    // [2048][1024] bf16
#define OFF_WO 8913152L    // [5056][640] bf16 (vocab rows padded w/ zeros)
#define OFF_EMB 15384832L  // [5000][512] bf16
#define OFF_ZB 20504832L   // [256][128] bf16
#define OFF_GB 20570368L   // [2][256][2048] bf16 (relu hidden of init MLP)
#define OFF_H0 22667520L   // [2][256][512] bf16 ping-pong
#define OFF_H1 23191808L   // [2][256][512] bf16 ping-pong
#define OFF_HS 23716096L   // [256][512] bf16 (h0+h1 for logits)
#define OFF_H0F 23978240L  // [256][512] f32
#define OFF_C0 24502528L   // [256][512] f32
#define OFF_C1 25026816L   // [256][512] f32
#define OFF_MB 25551104L   // [256][80] f32 per-tile max
#define OFF_SB 25633024L   // [256][80] f32 per-tile sumexp
#define OFF_TGT 25714944L  // [256] f32 target logit

__device__ __forceinline__ ushort f2bf(float f) {
  uint u = __float_as_uint(f);
  u = (u + 0x7fffu + ((u >> 16) & 1u)) >> 16;  // RNE
  return (ushort)u;
}

__device__ __forceinline__ float sigm(float v) { return 1.f / (1.f + __expf(-v)); }
__device__ __forceinline__ float tanh_f(float v) {
  float a = fabsf(v);
  float e = __expf(-2.f * a);
  float t = (1.f - e) / (1.f + e);
  return copysignf(t, v);
}

__device__ __forceinline__ f32x4 mfma16(bf16x8 a, bf16x8 b, f32x4 c) {
  return __builtin_amdgcn_mfma_f32_16x16x32_bf16(a, b, c, 0, 0, 0);
}

__device__ __forceinline__ bf16x8 ldbf8(const ushort* p) { return *(const bf16x8*)p; }

__device__ __forceinline__ bf16x8 cvt8(const float* p) {
  bf16x8 r;
#pragma unroll
  for (int j = 0; j < 8; ++j) r[j] = (__bf16)p[j];
  return r;
}

// 128x64 tile GEMM, one K-section. A row-major [*,Ksec] bf16 (4 per-msub row
// base ptrs), B row-major [N][K] bf16 (2 per-nsub col base ptrs, pre-offset
// to this K-section). Wave layout: 2(M)x2(N) waves, each 64x32 (4x2 mfma).
template <int NC>
__device__ __forceinline__ void gemm_bf(f32x4 (&acc)[4][2],
                                        const ushort* a0, const ushort* a1,
                                        const ushort* a2, const ushort* a3,
                                        const ushort* b0, const ushort* b1, int kln) {
#pragma unroll
  for (int kc = 0; kc < NC; ++kc) {
    const int kk = kc * 32 + kln;
    bf16x8 A0 = ldbf8(a0 + kk), A1 = ldbf8(a1 + kk), A2 = ldbf8(a2 + kk), A3 = ldbf8(a3 + kk);
    bf16x8 B0 = ldbf8(b0 + kk), B1 = ldbf8(b1 + kk);
    acc[0][0] = mfma16(A0, B0, acc[0][0]);
    acc[0][1] = mfma16(A0, B1, acc[0][1]);
    acc[1][0] = mfma16(A1, B0, acc[1][0]);
    acc[1][1] = mfma16(A1, B1, acc[1][1]);
    acc[2][0] = mfma16(A2, B0, acc[2][0]);
    acc[2][1] = mfma16(A2, B1, acc[2][1]);
    acc[3][0] = mfma16(A3, B0, acc[3][0]);
    acc[3][1] = mfma16(A3, B1, acc[3][1]);
  }
}

// same but B is fp32 (one-time init MLP weights, converted on the fly)
template <int NC>
__device__ __forceinline__ void gemm_bf_f32B(f32x4 (&acc)[4][2],
                                             const ushort* a0, const ushort* a1,
                                             const ushort* a2, const ushort* a3,
                                             const float* b0, const float* b1, int kln) {
#pragma unroll
  for (int kc = 0; kc < NC; ++kc) {
    const int kk = kc * 32 + kln;
    bf16x8 A0 = ldbf8(a0 + kk), A1 = ldbf8(a1 + kk), A2 = ldbf8(a2 + kk), A3 = ldbf8(a3 + kk);
    bf16x8 B0 = cvt8(b0 + kk), B1 = cvt8(b1 + kk);
    acc[0][0] = mfma16(A0, B0, acc[0][0]);
    acc[0][1] = mfma16(A0, B1, acc[0][1]);
    acc[1][0] = mfma16(A1, B0, acc[1][0]);
    acc[1][1] = mfma16(A1, B1, acc[1][1]);
    acc[2][0] = mfma16(A2, B0, acc[2][0]);
    acc[2][1] = mfma16(A2, B1, acc[2][1]);
    acc[3][0] = mfma16(A3, B0, acc[3][0]);
    acc[3][1] = mfma16(A3, B1, acc[3][1]);
  }
}

// C/D layout (16x16): col = lane&15, row = (lane>>4)*4 + reg  [m89/m91]
// LDS stride 68 floats: 4-rows-apart lanes land 16 banks apart (2-way max, free)
__device__ __forceinline__ void store_lds_tile(float* lds, f32x4 (&acc)[4][2], int wm, int wn,
                                               int lane) {
  const int l15 = lane & 15, lq = lane >> 4;
#pragma unroll
  for (int m = 0; m < 4; ++m)
#pragma unroll
    for (int n = 0; n < 2; ++n)
#pragma unroll
      for (int r = 0; r < 4; ++r)
        lds[(wm * 64 + m * 16 + lq * 4 + r) * 68 + (wn * 32 + n * 16 + l15)] = acc[m][n][r];
}

// monotonic-counter grid barrier; release add, relaxed spin, acquire fence.
__device__ __forceinline__ void grid_barrier(uint* bar, uint target) {
  __syncthreads();
  if (threadIdx.x == 0) {
    __hip_atomic_fetch_add(bar, 1u, __ATOMIC_RELEASE, __HIP_MEMORY_SCOPE_AGENT);
    while (__hip_atomic_load(bar, __ATOMIC_RELAXED, __HIP_MEMORY_SCOPE_AGENT) < target) {
      __builtin_amdgcn_s_sleep(2);
    }
    __builtin_amdgcn_fence(__ATOMIC_ACQUIRE, "agent");
  }
  __syncthreads();
}

// fused LSTM gate pointwise: tile is [128 b][16 d x 4 gates] in LDS
__device__ __forceinline__ void gates_pw(const float* lds, int tid, int b0, int d0,
                                         const float* __restrict__ bg, float* __restrict__ cbuf,
                                         ushort* __restrict__ hb, float* __restrict__ hf,
                                         ushort* __restrict__ hs, const float* __restrict__ h0f) {
  for (int i = tid; i < 2048; i += 256) {
    const int bl = i >> 4, dq = i & 15;
    const f32x4 g = ((const f32x4*)lds)[bl * 17 + dq];
    const int d = d0 + dq;
    const int idx = (b0 + bl) * 512 + d;
    const float gi = g[0] + bg[d];
    const float gf = g[1] + bg[512 + d];
    const float go = g[2] + bg[1024 + d];
    const float gc = g[3] + bg[1536 + d];
    const float ii = sigm(gi), ff = sigm(gf), oo = sigm(go), cn = tanh_f(gc);
    const float c = ff * cbuf[idx] + ii * cn;
    cbuf[idx] = c;
    const float h = oo * tanh_f(c);
    hb[idx] = f2bf(h);
    if (hf) hf[idx] = h;
    if (hs) hs[idx] = f2bf(h + h0f[idx]);
  }
}

__device__ __forceinline__ float combine_row(const float* __restrict__ MB,
                                             const float* __restrict__ SB,
                                             const float* __restrict__ TGT, int r, int lane) {
  float M = MB[r * 80 + lane];
  float S = SB[r * 80 + lane];
  if (lane < 15) {  // tiles 64..78
    const float m2 = MB[r * 80 + 64 + lane], s2 = SB[r * 80 + 64 + lane];
    const float Mn = fmaxf(M, m2);
    S = S * __expf(M - Mn) + s2 * __expf(m2 - Mn);
    M = Mn;
  }
#pragma unroll
  for (int off = 32; off > 0; off >>= 1) {
    const float Mo = __shfl_xor(M, off, 64);
    const float So = __shfl_xor(S, off, 64);
    const float Mn = fmaxf(M, Mo);
    S = S * __expf(M - Mn) + So * __expf(Mo - Mn);
    M = Mn;
  }
  return TGT[r] - (M + __logf(S));
}

// ---------------------------------------------------------------------------
__global__ void __launch_bounds__(256) prep_kernel(const float* __restrict__ Wg0,
                                                   const float* __restrict__ Wg1,
                                                   const float* __restrict__ Wout,
                                                   const float* __restrict__ emb,
                                                   const float* __restrict__ z,
                                                   unsigned char* __restrict__ ws) {
  ushort* W0p = (ushort*)(ws + OFF_W0);
  ushort* W1p = (ushort*)(ws + OFF_W1);
  ushort* WOp = (ushort*)(ws + OFF_WO);
  ushort* EMBB = (ushort*)(ws + OFF_EMB);
  ushort* ZB = (ushort*)(ws + OFF_ZB);
  const long E0 = 2048L * 1152, E1 = 2048L * 1024, E2 = 5056L * 640, E3 = 5000L * 512,
             E4 = 256L * 128;
  const long total = E0 + E1 + E2 + E3 + E4;
  const long stride = (long)gridDim.x * blockDim.x;
  for (long i = (long)blockIdx.x * blockDim.x + threadIdx.x; i < total; i += stride) {
    long j = i;
    if (j < E0) {  // gate-interleaved: dst row r = d*4+g <- src Wg0[g][d][:]
      const int r = (int)(j / 1152), f = (int)(j - (long)r * 1152);
      W0p[j] = f2bf(Wg0[(long)((r & 3) * 512 + (r >> 2)) * 1152 + f]);
    } else if ((j -= E0) < E1) {
      const int r = (int)(j >> 10), f = (int)(j & 1023);
      W1p[j] = f2bf(Wg1[(long)((r & 3) * 512 + (r >> 2)) * 1024 + f]);
    } else if ((j -= E1) < E2) {
      const int r = (int)(j / 640), c = (int)(j - (long)r * 640);
      WOp[j] = (r < 5000) ? f2bf(Wout[(long)r * 640 + c]) : (ushort)0;
    } else if ((j -= E2) < E3) {
      EMBB[j] = f2bf(emb[j]);
    } else {
      j -= E3;
      ZB[j] = f2bf(z[j]);
    }
  }
}

// ---------------------------------------------------------------------------
__global__ void __launch_bounds__(256, 1) decoder_main(
    const int* __restrict__ x, const float* __restrict__ bg0, const float* __restrict__ bg1,
    const float* __restrict__ bout, const float* __restrict__ tw1, const float* __restrict__ tb1,
    const float* __restrict__ tw2, const float* __restrict__ tb2, unsigned char* __restrict__ ws,
    float* __restrict__ out) {
  __shared__ float lds[128 * 68];

  uint* bar = (uint*)(ws + OFF_BAR);
  ushort* W0p = (ushort*)(ws + OFF_W0);
  ushort* W1p = (ushort*)(ws + OFF_W1);
  ushort* WOp = (ushort*)(ws + OFF_WO);
  ushort* EMBB = (ushort*)(ws + OFF_EMB);
  ushort* ZB = (ushort*)(ws + OFF_ZB);
  ushort* GB = (ushort*)(ws + OFF_GB);
  ushort* H0B = (ushort*)(ws + OFF_H0);
  ushort* H1B = (ushort*)(ws + OFF_H1);
  ushort* HSB = (ushort*)(ws + OFF_HS);
  float* H0F = (float*)(ws + OFF_H0F);
  float* C0 = (float*)(ws + OFF_C0);
  float* C1 = (float*)(ws + OFF_C1);
  float* MB = (float*)(ws + OFF_MB);
  float* SB = (float*)(ws + OFF_SB);
  float* TGT = (float*)(ws + OFF_TGT);

  const int bid = blockIdx.x;
  const int tid = threadIdx.x;
  const int lane = tid & 63;
  const int w = tid >> 6;
  const int wm = w & 1, wn = w >> 1;
  const int l15 = lane & 15;
  const int kln = (lane >> 4) * 8;

  uint btgt = 0;

  // ======== init1: G[l] = relu(z @ tw1[l].T + tb1[l]), N=4096 combined ========
  if (bid < 128) {
    const int mt = bid & 1, nt = bid >> 1;
    const int b0 = mt * 128, n0 = nt * 64;
    f32x4 acc[4][2];
#pragma unroll
    for (int m = 0; m < 4; ++m)
#pragma unroll
      for (int n = 0; n < 2; ++n) acc[m][n] = (f32x4){0.f, 0.f, 0.f, 0.f};
    const ushort* a[4];
#pragma unroll
    for (int m = 0; m < 4; ++m) a[m] = ZB + (b0 + wm * 64 + m * 16 + l15) * 128;
    const int c0i = n0 + wn * 32 + l15;
    gemm_bf_f32B<4>(acc, a[0], a[1], a[2], a[3], tw1 + (long)c0i * 128,
                    tw1 + (long)(c0i + 16) * 128, kln);
    store_lds_tile(lds, acc, wm, wn, lane);
    __syncthreads();
    for (int i = tid; i < 2048; i += 256) {
      const int bl = i >> 4, q = i & 15;
      const f32x4 v = ((const f32x4*)lds)[bl * 17 + q];
      const int colb = n0 + q * 4;
      const int l = colb >> 11, rr = colb & 2047;
      ushort4v o;
#pragma unroll
      for (int cc = 0; cc < 4; ++cc) o[cc] = f2bf(fmaxf(v[cc] + tb1[colb + cc], 0.f));
      *(ushort4v*)(GB + (long)l * (256 * 2048) + (long)(b0 + bl) * 2048 + rr) = o;
    }
  }
  btgt += 256;
  grid_barrier(bar, btgt);

  // ======== init2: hh = tanh(G[l] @ tw2[l].T + tb2[l]) -> (h,c) states ========
  if (bid < 64) {
    const int mt = bid & 1, nt = bid >> 1;
    const int b0 = mt * 128, n0 = nt * 64;
    const int l = n0 >> 10;  // block entirely within one layer
    f32x4 acc[4][2];
#pragma unroll
    for (int m = 0; m < 4; ++m)
#pragma unroll
      for (int n = 0; n < 2; ++n) acc[m][n] = (f32x4){0.f, 0.f, 0.f, 0.f};
    const ushort* a[4];
#pragma unroll
    for (int m = 0; m < 4; ++m)
      a[m] = GB + (long)l * (256 * 2048) + (long)(b0 + wm * 64 + m * 16 + l15) * 2048;
    const int c0i = n0 + wn * 32 + l15;
    const float* bb0 = tw2 + (long)c0i * 2048;
    const float* bb1 = tw2 + (long)(c0i + 16) * 2048;
#pragma unroll
    for (int s = 0; s < 4; ++s)  // K=2048 in 4 sections of 512
      gemm_bf_f32B<16>(acc, a[0] + s * 512, a[1] + s * 512, a[2] + s * 512, a[3] + s * 512,
                       bb0 + s * 512, bb1 + s * 512, kln);
    store_lds_tile(lds, acc, wm, wn, lane);
    __syncthreads();
    for (int i = tid; i < 2048; i += 256) {
      const int bl = i >> 4, q = i & 15;
      const f32x4 v = ((const f32x4*)lds)[bl * 17 + q];
      const int colb = n0 + q * 4;
      const int ll = colb >> 10, rr = colb & 1023;
      const int b = b0 + bl;
      if (rr < 512) {
        ushort4v o;
#pragma unroll
        for (int cc = 0; cc < 4; ++cc) o[cc] = f2bf(tanh_f(v[cc] + tb2[colb + cc]));
        *(ushort4v*)((ll ? H1B : H0B) + b * 512 + rr) = o;  // ping buffer 0
      } else {
        f32x4 o;
#pragma unroll
        for (int cc = 0; cc < 4; ++cc) o[cc] = tanh_f(v[cc] + tb2[colb + cc]);
        *(f32x4*)((ll ? C1 : C0) + b * 512 + (rr - 512)) = o;
      }
    }
  }
  btgt += 256;
  grid_barrier(bar, btgt);

  float accO1 = 0.f, accO2 = 0.f;

  for (int t = 0; t < 40; ++t) {
    const int p = t & 1;
    ushort* h0r = H0B + p * (256 * 512);
    ushort* h0w = H0B + (1 - p) * (256 * 512);
    ushort* h1r = H1B + p * (256 * 512);
    ushort* h1w = H1B + (1 - p) * (256 * 512);

    // ---------------- phase 1: L0 gates || logits(h_{t-1}) ----------------
    if (bid < 64) {
      const int mt = bid & 1, nt = bid >> 1;
      const int b0 = mt * 128, n0 = nt * 64;
      f32x4 acc[4][2];
#pragma unroll
      for (int m = 0; m < 4; ++m)
#pragma unroll
        for (int n = 0; n < 2; ++n) acc[m][n] = (f32x4){0.f, 0.f, 0.f, 0.f};
      const ushort *ah[4], *ae[4], *az[4];
#pragma unroll
      for (int m = 0; m < 4; ++m) {
        const int r = b0 + wm * 64 + m * 16 + l15;
        ah[m] = h0r + r * 512;
        ae[m] = EMBB + (long)x[r * 40 + t] * 512;
        az[m] = ZB + r * 128;
      }
      const ushort* bc0 = W0p + (long)(n0 + wn * 32 + l15) * 1152;
      const ushort* bc1 = bc0 + 16L * 1152;
      gemm_bf<16>(acc, ah[0], ah[1], ah[2], ah[3], bc0, bc1, kln);              // hx[0:512]=h0
      gemm_bf<16>(acc, ae[0], ae[1], ae[2], ae[3], bc0 + 512, bc1 + 512, kln);  // [512:1024]=e_t
      gemm_bf<4>(acc, az[0], az[1], az[2], az[3], bc0 + 1024, bc1 + 1024, kln); // [1024:1152]=z
      store_lds_tile(lds, acc, wm, wn, lane);
      __syncthreads();
      gates_pw(lds, tid, b0, nt * 16, bg0, C0, h0w, H0F, nullptr, nullptr);
    } else if (t >= 1 && bid < 222) {
      const int tile = bid - 64;
      const int mt = tile & 1, nt = tile >> 1;  // nt 0..78
      const int b0 = mt * 128, n0 = nt * 64;
      f32x4 acc[4][2];
#pragma unroll
      for (int m = 0; m < 4; ++m)
#pragma unroll
        for (int n = 0; n < 2; ++n) acc[m][n] = (f32x4){0.f, 0.f, 0.f, 0.f};
      const ushort *ah[4], *az[4];
#pragma unroll
      for (int m = 0; m < 4; ++m) {
        const int r = b0 + wm * 64 + m * 16 + l15;
        ah[m] = HSB + r * 512;
        az[m] = ZB + r * 128;
      }
      const ushort* bc0 = WOp + (long)(n0 + wn * 32 + l15) * 640;
      const ushort* bc1 = bc0 + 16L * 640;
      gemm_bf<16>(acc, ah[0], ah[1], ah[2], ah[3], bc0, bc1, kln);
      gemm_bf<4>(acc, az[0], az[1], az[2], az[3], bc0 + 512, bc1 + 512, kln);
      store_lds_tile(lds, acc, wm, wn, lane);
      __syncthreads();
      if (tid < 128) {  // one thread per batch row: tile max / sumexp / target
        const int b = b0 + tid;
        const f32x4* row4 = (const f32x4*)lds + tid * 17;
        const int xt = x[b * 40 + t];
        float mx = -3.0e38f, tv = 0.f;
        const bool hast = (xt >= n0 && xt < n0 + 64);
        for (int j = 0; j < 16; ++j) {
          const f32x4 v = row4[j];
#pragma unroll
          for (int cc = 0; cc < 4; ++cc) {
            const int col = n0 + j * 4 + cc;
            if (col < 5000) {
              const float val = v[cc] + bout[col];
              mx = fmaxf(mx, val);
              if (col == xt) tv = val;
            }
          }
        }
        float s = 0.f;
        for (int j = 0; j < 16; ++j) {
          const f32x4 v = row4[j];
#pragma unroll
          for (int cc = 0; cc < 4; ++cc) {
            const int col = n0 + j * 4 + cc;
            if (col < 5000) s += __expf(v[cc] + bout[col] - mx);
          }
        }
        MB[b * 80 + nt] = mx;
        SB[b * 80 + nt] = s;
        if (hast) TGT[b] = tv;
      }
    }
    btgt += 256;
    grid_barrier(bar, btgt);

    // ---------------- phase 2: L1 gates || logsumexp-combine ----------------
    if (bid < 64) {
      const int mt = bid & 1, nt = bid >> 1;
      const int b0 = mt * 128, n0 = nt * 64;
      f32x4 acc[4][2];
#pragma unroll
      for (int m = 0; m < 4; ++m)
#pragma unroll
        for (int n = 0; n < 2; ++n) acc[m][n] = (f32x4){0.f, 0.f, 0.f, 0.f};
      const ushort *a1[4], *a0[4];
#pragma unroll
      for (int m = 0; m < 4; ++m) {
        const int r = b0 + wm * 64 + m * 16 + l15;
        a1[m] = h1r + r * 512;  // hx[0:512]   = h1_{t-1}
        a0[m] = h0w + r * 512;  // hx[512:1024]= h0_t (written in phase 1)
      }
      const ushort* bc0 = W1p + (long)(n0 + wn * 32 + l15) * 1024;
      const ushort* bc1 = bc0 + 16L * 1024;
      gemm_bf<16>(acc, a1[0], a1[1], a1[2], a1[3], bc0, bc1, kln);
      gemm_bf<16>(acc, a0[0], a0[1], a0[2], a0[3], bc0 + 512, bc1 + 512, kln);
      store_lds_tile(lds, acc, wm, wn, lane);
      __syncthreads();
      gates_pw(lds, tid, b0, nt * 16, bg1, C1, h1w, nullptr, HSB, H0F);
    } else if (t >= 1) {
      if (w == 0) {
        const int r1 = bid - 64;  // 0..191
        accO1 += combine_row(MB, SB, TGT, r1, lane);
        if (r1 < 64) accO2 += combine_row(MB, SB, TGT, r1 + 192, lane);
      }
    }
    btgt += 256;
    grid_barrier(bar, btgt);
  }

  if (bid >= 64 && tid == 0) {
    const int r1 = bid - 64;
    out[r1] = accO1;
    if (r1 < 64) out[r1 + 192] = accO2;
  }
}

// ---------------------------------------------------------------------------
extern "C" void kernel_launch(void* const* d_in, const int* in_sizes, int n_in, void* d_out,
                              int out_size, void* d_ws, size_t ws_size, hipStream_t stream) {
  const float* z = (const float*)d_in[0];
  const int* x = (const int*)d_in[1];
  const float* emb = (const float*)d_in[2];
  const float* Wg0 = (const float*)d_in[3];
  const float* bg0 = (const float*)d_in[4];
  const float* Wg1 = (const float*)d_in[5];
  const float* bg1 = (const float*)d_in[6];
  const float* Wout = (const float*)d_in[7];
  const float* bout = (const float*)d_in[8];
  const float* tw1 = (const float*)d_in[9];
  const float* tb1 = (const float*)d_in[10];
  const float* tw2 = (const float*)d_in[11];
  const float* tb2 = (const float*)d_in[12];
  unsigned char* ws = (unsigned char*)d_ws;
  float* out = (float*)d_out;

  hipMemsetAsync(ws, 0, 256, stream);  // grid-barrier counter
  prep_kernel<<<2048, 256, 0, stream>>>(Wg0, Wg1, Wout, emb, z, ws);
  decoder_main<<<256, 256, 0, stream>>>(x, bg0, bg1, bout, tw1, tb1, tw2, tb2, ws, out);
}

// Round 2
// 2611.774 us; speedup vs baseline: 1.5160x; 1.5160x over previous
//
#include <hip/hip_runtime.h>

// ============================================================================
// Persistent-kernel LSTM decoder for MI355X (gfx950) — round 2.
// All GEMMs: bf16 MFMA 16x16x32, operands staged via global_load_lds into a
// 3-slot LDS ring with raw s_barrier + s_waitcnt vmcnt(12) (no vmcnt(0) drain
// in the K-loop). All operands pre-swizzled into MFMA-fragment-tile layouts.
// Grid sync: 256-flag release/acquire barrier (no serialized atomics).
// ============================================================================

typedef unsigned int uint;
typedef unsigned short ushort;
typedef __attribute__((ext_vector_type(8))) __bf16 bf16x8;
typedef __attribute__((ext_vector_type(4))) float f32x4;
typedef __attribute__((ext_vector_type(4))) ushort ushort4v;
typedef __attribute__((ext_vector_type(8))) ushort ushort8v;

// ---- workspace byte offsets ----
#define OFF_FLAGS 0L         // 256 x u32
#define OFF_W0    1024L      // [32 ng][36 kc] B-frag tiles, 2048x1152 bf16
#define OFF_W1    4719616L   // [32 ng][32 kc], 2048x1024
#define OFF_WO    8913920L   // [80 ng][20 kc], 5120x640 (vocab-padded)
#define OFF_EFT   15467520L  // [40 t][2 mt][16 kc] A-frag, gathered emb
#define OFF_ZFT   25953280L  // [2 mt][4 kc] A-frag of z
#define OFF_TW1   26018816L  // [64 ng][4 kc], 4096x128
#define OFF_TW2   27067392L  // [32 ng][64 kc], 2048x2048
#define OFF_GB    35456000L  // [2 l][2 mt][64 kc] A-frag relu hidden
#define OFF_H0    37553152L  // [2 par][2 mt][16 kc] A-frag h0
#define OFF_H1    38077440L  // [2 par] h1
#define OFF_HS    38601728L  // [2 par] h0+h1 (logits A)
#define OFF_H0F   39126016L  // [256][512] f32 h0 (linear)
#define OFF_C0    39650304L  // [256][512] f32
#define OFF_C1    40174592L  // [256][512] f32
#define OFF_MB    40698880L  // [2 par][256][80] f32
#define OFF_SB    40862720L
#define OFF_TGT   41026560L  // [2 par][256] f32
// total ~41,028,608 bytes

#define HPAR 262144L  // bytes per parity of an A-frag [2mt][16kc] buffer
#define HMT  131072L  // bytes per mt

__device__ __forceinline__ ushort f2bf(float f) {
  uint u = __float_as_uint(f);
  u = (u + 0x7fffu + ((u >> 16) & 1u)) >> 16;  // RNE
  return (ushort)u;
}
__device__ __forceinline__ float sigm(float v) { return 1.f / (1.f + __expf(-v)); }
__device__ __forceinline__ float tanh_f(float v) {
  float a = fabsf(v);
  float e = __expf(-2.f * a);
  return copysignf((1.f - e) / (1.f + e), v);
}
__device__ __forceinline__ f32x4 mfma16(bf16x8 a, bf16x8 b, f32x4 c) {
  return __builtin_amdgcn_mfma_f32_16x16x32_bf16(a, b, c, 0, 0, 0);
}

// A-fragment-tile element index for a [256 rows][K] matrix, KC = K/32.
// chunk = 128rows x 32k = 4096 elems: [r8(8)][kq(4)][row16(16)][k8(8)].
__device__ __forceinline__ long fta(int b, int k, int KC) {
  return ((long)(((b >> 7) & 1) * KC + (k >> 5)) << 12) +
         (((((b >> 4) & 7) << 2) + ((k >> 3) & 3)) << 7) + ((b & 15) << 3) + (k & 7);
}

__device__ __forceinline__ void gl_lds16(const char* g, char* l) {
  __builtin_amdgcn_global_load_lds((const __attribute__((address_space(1))) void*)g,
                                   (__attribute__((address_space(3))) void*)l, 16, 0, 0);
}

// stage one section: A = 4 chunks x 8KB = 32KB, B = 4 chunks x 4KB = 16KB.
__device__ __forceinline__ void stage_sec(const char* A, const char* B, char* lb, int tid) {
  const int o = tid * 16;
#pragma unroll
  for (int i = 0; i < 8; ++i) gl_lds16(A + i * 4096 + o, lb + i * 4096 + o);
#pragma unroll
  for (int i = 0; i < 4; ++i) gl_lds16(B + i * 4096 + o, lb + 32768 + i * 4096 + o);
}

__device__ __forceinline__ void secp(int s, int n0, int n1, const char* A0, const char* B0,
                                     const char* A1, const char* B1, const char* A2,
                                     const char* B2, const char*& A, const char*& B) {
  if (s < n0) {
    A = A0 + (long)s * 32768;
    B = B0 + (long)s * 16384;
  } else if (s < n0 + n1) {
    const int q = s - n0;
    A = A1 + (long)q * 32768;
    B = B1 + (long)q * 16384;
  } else {
    const int q = s - n0 - n1;
    A = A2 + (long)q * 32768;
    B = B2 + (long)q * 16384;
  }
}

// 128x64 tile GEMM over up to 3 K-segments (S sections of 128 k).
// Ring-3 LDS staging; raw s_barrier + vmcnt(12) so prefetch stays in flight.
__device__ __forceinline__ void run_gemm(const char* A0, const char* B0, int n0, const char* A1,
                                         const char* B1, int n1, const char* A2, const char* B2,
                                         int S, char* smem, int tid, int wm, int wn, int lane,
                                         f32x4 (&acc)[4][2]) {
  {
    const char *A, *B;
    secp(0, n0, n1, A0, B0, A1, B1, A2, B2, A, B);
    stage_sec(A, B, smem, tid);
  }
  if (S > 1) {
    const char *A, *B;
    secp(1, n0, n1, A0, B0, A1, B1, A2, B2, A, B);
    stage_sec(A, B, smem + 49152, tid);
  }
  const int ab = wm * 4096 + lane * 16;
  const int bb = 32768 + wn * 2048 + lane * 16;
  for (int s = 0; s < S; ++s) {
    if (s + 1 < S)
      __builtin_amdgcn_s_waitcnt(0x0F7C);  // vmcnt(12): oldest section done, next in flight
    else
      __builtin_amdgcn_s_waitcnt(0x0F70);  // vmcnt(0): tail
    __builtin_amdgcn_s_barrier();
    char* sb = smem + (s % 3) * 49152;
    if (s + 2 < S) {
      const char *A, *B;
      secp(s + 2, n0, n1, A0, B0, A1, B1, A2, B2, A, B);
      stage_sec(A, B, smem + ((s + 2) % 3) * 49152, tid);
    }
#pragma unroll
    for (int c = 0; c < 4; ++c) {
      const char* ap = sb + c * 8192 + ab;
      const char* bp = sb + c * 4096 + bb;
      bf16x8 Af0 = *(const bf16x8*)(ap);
      bf16x8 Af1 = *(const bf16x8*)(ap + 1024);
      bf16x8 Af2 = *(const bf16x8*)(ap + 2048);
      bf16x8 Af3 = *(const bf16x8*)(ap + 3072);
      bf16x8 Bf0 = *(const bf16x8*)(bp);
      bf16x8 Bf1 = *(const bf16x8*)(bp + 1024);
      acc[0][0] = mfma16(Af0, Bf0, acc[0][0]);
      acc[0][1] = mfma16(Af0, Bf1, acc[0][1]);
      acc[1][0] = mfma16(Af1, Bf0, acc[1][0]);
      acc[1][1] = mfma16(Af1, Bf1, acc[1][1]);
      acc[2][0] = mfma16(Af2, Bf0, acc[2][0]);
      acc[2][1] = mfma16(Af2, Bf1, acc[2][1]);
      acc[3][0] = mfma16(Af3, Bf0, acc[3][0]);
      acc[3][1] = mfma16(Af3, Bf1, acc[3][1]);
    }
  }
  __syncthreads();
}

// C/D layout: col = lane&15, row = (lane>>4)*4 + reg; f32 tile stride 68.
__device__ __forceinline__ void store_lds_tile(float* lds, f32x4 (&acc)[4][2], int wm, int wn,
                                               int lane) {
  const int l15 = lane & 15, lq = lane >> 4;
#pragma unroll
  for (int m = 0; m < 4; ++m)
#pragma unroll
    for (int n = 0; n < 2; ++n)
#pragma unroll
      for (int r = 0; r < 4; ++r)
        lds[(wm * 64 + m * 16 + lq * 4 + r) * 68 + (wn * 32 + n * 16 + l15)] = acc[m][n][r];
}

// flag-array grid barrier: parallel release stores, per-thread poll, acquire.
__device__ __forceinline__ void grid_barrier(uint* flags, uint target) {
  __syncthreads();
  if (threadIdx.x == 0)
    __hip_atomic_store(&flags[blockIdx.x], target, __ATOMIC_RELEASE, __HIP_MEMORY_SCOPE_AGENT);
  uint v = __hip_atomic_load(&flags[threadIdx.x], __ATOMIC_RELAXED, __HIP_MEMORY_SCOPE_AGENT);
  while (v < target) {
    __builtin_amdgcn_s_sleep(1);
    v = __hip_atomic_load(&flags[threadIdx.x], __ATOMIC_RELAXED, __HIP_MEMORY_SCOPE_AGENT);
  }
  __builtin_amdgcn_fence(__ATOMIC_ACQUIRE, "agent");
  __syncthreads();
}

// LSTM gate pointwise; tile = [128 b][16 d x 4 gates] f32; h written fragment-tiled.
__device__ __forceinline__ void gates_pw_ft(const float* tile, int tid, int b0, int d0,
                                            const float* __restrict__ bg, float* __restrict__ cbuf,
                                            ushort* __restrict__ hft, float* __restrict__ hf,
                                            ushort* __restrict__ hsft,
                                            const float* __restrict__ h0f) {
  for (int i = tid; i < 2048; i += 256) {
    const int bl = i >> 4, dq = i & 15;
    const f32x4 g = ((const f32x4*)tile)[bl * 17 + dq];
    const int d = d0 + dq, b = b0 + bl;
    const int idx = b * 512 + d;
    const float gi = g[0] + bg[d];
    const float gf = g[1] + bg[512 + d];
    const float go = g[2] + bg[1024 + d];
    const float gc = g[3] + bg[1536 + d];
    const float ii = sigm(gi), ff = sigm(gf), oo = sigm(go), cn = tanh_f(gc);
    const float c = ff * cbuf[idx] + ii * cn;
    cbuf[idx] = c;
    const float h = oo * tanh_f(c);
    const long ft = fta(b, d, 16);
    hft[ft] = f2bf(h);
    if (hf) hf[idx] = h;
    if (hsft) hsft[ft] = f2bf(h + h0f[idx]);
  }
}

__device__ __forceinline__ void logits_epi(const float* tile, int tid, int b0, int ng, int t,
                                           const int* __restrict__ x,
                                           const float* __restrict__ bout, float* __restrict__ MBp,
                                           float* __restrict__ SBp, float* __restrict__ TGTp) {
  if (tid >= 128) return;
  const int b = b0 + tid;
  const f32x4* row4 = (const f32x4*)tile + tid * 17;
  const int xt = x[b * 40 + t];
  const int n0 = ng * 64;
  float mx = -3.0e38f, tv = 0.f;
  for (int j = 0; j < 16; ++j) {
    const f32x4 v = row4[j];
#pragma unroll
    for (int cc = 0; cc < 4; ++cc) {
      const int col = n0 + j * 4 + cc;
      if (col < 5000) {
        const float val = v[cc] + bout[col];
        mx = fmaxf(mx, val);
        if (col == xt) tv = val;
      }
    }
  }
  float s = 0.f;
  for (int j = 0; j < 16; ++j) {
    const f32x4 v = row4[j];
#pragma unroll
    for (int cc = 0; cc < 4; ++cc) {
      const int col = n0 + j * 4 + cc;
      if (col < 5000) s += __expf(v[cc] + bout[col] - mx);
    }
  }
  MBp[b * 80 + ng] = mx;
  SBp[b * 80 + ng] = s;
  if (xt >= n0 && xt < n0 + 64) TGTp[b] = tv;
}

__device__ __forceinline__ float combine_row(const float* __restrict__ MBc,
                                             const float* __restrict__ SBc,
                                             const float* __restrict__ TGTc, int r, int lane) {
  float M = MBc[r * 80 + lane];
  float S = SBc[r * 80 + lane];
  if (lane < 16) {  // fold tiles 64..79
    const float m2 = MBc[r * 80 + 64 + lane], s2 = SBc[r * 80 + 64 + lane];
    const float Mn = fmaxf(M, m2);
    S = S * __expf(M - Mn) + s2 * __expf(m2 - Mn);
    M = Mn;
  }
#pragma unroll
  for (int off = 32; off > 0; off >>= 1) {
    const float Mo = __shfl_xor(M, off, 64);
    const float So = __shfl_xor(S, off, 64);
    const float Mn = fmaxf(M, Mo);
    S = S * __expf(M - Mn) + So * __expf(Mo - Mn);
    M = Mn;
  }
  return TGTc[r] - (M + __logf(S));
}

// ---------------------------------------------------------------------------
// prep: fp32 -> bf16 + swizzle everything into fragment-tile layouts;
// pre-gather embeddings for all 40 steps.
__device__ __forceinline__ void cv8(ushort8v& o, const float* s) {
  const f32x4 a = *(const f32x4*)s, b = *(const f32x4*)(s + 4);
#pragma unroll
  for (int j = 0; j < 4; ++j) o[j] = f2bf(a[j]);
#pragma unroll
  for (int j = 0; j < 4; ++j) o[4 + j] = f2bf(b[j]);
}
__device__ __forceinline__ void bft8(ushort* dst, int col, int kg, int KC, const float* src) {
  ushort8v o;
  cv8(o, src);
  *(ushort8v*)(dst + ((long)((col >> 6) * KC + (kg >> 2)) << 11) +
               (((((col >> 4) & 3) << 2) + (kg & 3)) << 7) + ((col & 15) << 3)) = o;
}
__device__ __forceinline__ void bft8z(ushort* dst, int col, int kg, int KC) {
  ushort8v o = (ushort8v)0;
  *(ushort8v*)(dst + ((long)((col >> 6) * KC + (kg >> 2)) << 11) +
               (((((col >> 4) & 3) << 2) + (kg & 3)) << 7) + ((col & 15) << 3)) = o;
}
__device__ __forceinline__ void aft8(ushort* dst, int b, int kg, int KC, const float* src) {
  ushort8v o;
  cv8(o, src);
  *(ushort8v*)(dst + ((long)(((b >> 7) & 1) * KC + (kg >> 2)) << 12) +
               (((((b >> 4) & 7) << 2) + (kg & 3)) << 7) + ((b & 15) << 3)) = o;
}

__global__ void __launch_bounds__(256) prep_kernel(
    const float* __restrict__ Wg0, const float* __restrict__ Wg1, const float* __restrict__ Wout,
    const float* __restrict__ emb, const float* __restrict__ z, const int* __restrict__ x,
    const float* __restrict__ tw1, const float* __restrict__ tw2, unsigned char* __restrict__ ws) {
  ushort* W0 = (ushort*)(ws + OFF_W0);
  ushort* W1 = (ushort*)(ws + OFF_W1);
  ushort* WO = (ushort*)(ws + OFF_WO);
  ushort* EF = (ushort*)(ws + OFF_EFT);
  ushort* ZF = (ushort*)(ws + OFF_ZFT);
  ushort* T1 = (ushort*)(ws + OFF_TW1);
  ushort* T2 = (ushort*)(ws + OFF_TW2);
  const long N0 = 294912, N1 = 262144, N2 = 409600, N3 = 655360, N4 = 4096, N5 = 65536,
             N6 = 524288;
  const long total = N0 + N1 + N2 + N3 + N4 + N5 + N6;
  for (long idx = (long)blockIdx.x * 256 + threadIdx.x; idx < total;
       idx += (long)gridDim.x * 256) {
    long j = idx;
    if (j < N0) {  // W0: gate-interleaved col r=d*4+g
      const int col = (int)(j / 144), kg = (int)(j - (long)col * 144);
      bft8(W0, col, kg, 36, Wg0 + (long)((col & 3) * 512 + (col >> 2)) * 1152 + kg * 8);
    } else if ((j -= N0) < N1) {
      const int col = (int)(j >> 7), kg = (int)(j & 127);
      bft8(W1, col, kg, 32, Wg1 + (long)((col & 3) * 512 + (col >> 2)) * 1024 + kg * 8);
    } else if ((j -= N1) < N2) {
      const int col = (int)(j / 80), kg = (int)(j - (long)col * 80);
      if (col < 5000)
        bft8(WO, col, kg, 20, Wout + (long)col * 640 + kg * 8);
      else
        bft8z(WO, col, kg, 20);
    } else if ((j -= N2) < N3) {  // emb gather, all t
      const int t = (int)(j >> 14), r = (int)(j & 16383);
      const int b = r >> 6, kg = r & 63;
      aft8(EF + (long)t * 131072, b, kg, 16, emb + (long)x[b * 40 + t] * 512 + kg * 8);
    } else if ((j -= N3) < N4) {
      const int b = (int)(j >> 4), kg = (int)(j & 15);
      aft8(ZF, b, kg, 4, z + b * 128 + kg * 8);
    } else if ((j -= N4) < N5) {
      const int col = (int)(j >> 4), kg = (int)(j & 15);
      bft8(T1, col, kg, 4, tw1 + (long)(col >> 11) * 262144 + (long)(col & 2047) * 128 + kg * 8);
    } else {
      j -= N5;
      const int col = (int)(j >> 8), kg = (int)(j & 255);
      bft8(T2, col, kg, 64, tw2 + (long)(col >> 10) * 2097152 + (long)(col & 1023) * 2048 + kg * 8);
    }
  }
}

// ---------------------------------------------------------------------------
__global__ void __launch_bounds__(256) decoder_main(
    const int* __restrict__ x, const float* __restrict__ bg0, const float* __restrict__ bg1,
    const float* __restrict__ bout, const float* __restrict__ tb1, const float* __restrict__ tb2,
    unsigned char* __restrict__ ws, float* __restrict__ out) {
  __shared__ __align__(16) char smem[147456];  // 3 x 49152 ring; epilogue tile aliases slot 0

  uint* flags = (uint*)(ws + OFF_FLAGS);
  const char* cW0 = (const char*)(ws + OFF_W0);
  const char* cW1 = (const char*)(ws + OFF_W1);
  const char* cWO = (const char*)(ws + OFF_WO);
  const char* cEF = (const char*)(ws + OFF_EFT);
  const char* cZF = (const char*)(ws + OFF_ZFT);
  const char* cT1 = (const char*)(ws + OFF_TW1);
  const char* cT2 = (const char*)(ws + OFF_TW2);
  char* cGB = (char*)(ws + OFF_GB);
  char* cH0 = (char*)(ws + OFF_H0);
  char* cH1 = (char*)(ws + OFF_H1);
  char* cHS = (char*)(ws + OFF_HS);
  float* H0F = (float*)(ws + OFF_H0F);
  float* C0f = (float*)(ws + OFF_C0);
  float* C1f = (float*)(ws + OFF_C1);
  float* MBf = (float*)(ws + OFF_MB);
  float* SBf = (float*)(ws + OFF_SB);
  float* TGTf = (float*)(ws + OFF_TGT);

  const int bid = blockIdx.x;
  const int tid = threadIdx.x;
  const int lane = tid & 63;
  const int w = tid >> 6;
  const int wm = w & 1, wn = w >> 1;
  const int xcd = bid & 7;   // assumed round-robin block->XCD (perf heuristic only)
  const int slot = bid >> 3; // 0..31 within XCD

  uint bt = 0;
  float accO0 = 0.f, accO1 = 0.f;

  // ======== init1: relu(z @ tw1^T + tb1) -> GB (A-frag layout) ========
  if (slot < 16) {
    const int i_mt = slot & 1, i_ng = xcd * 8 + (slot >> 1);
    f32x4 acc[4][2];
#pragma unroll
    for (int m = 0; m < 4; ++m)
#pragma unroll
      for (int n = 0; n < 2; ++n) acc[m][n] = (f32x4){0.f, 0.f, 0.f, 0.f};
    run_gemm(cZF + (long)i_mt * 32768, cT1 + (long)i_ng * 16384, 4, nullptr, nullptr, 0, nullptr,
             nullptr, 1, smem, tid, wm, wn, lane, acc);
    store_lds_tile((float*)smem, acc, wm, wn, lane);
    __syncthreads();
    const int b0i = i_mt * 128, n0i = i_ng * 64;
    ushort* GBu = (ushort*)cGB;
    for (int i = tid; i < 2048; i += 256) {
      const int bl = i >> 4, q = i & 15;
      const f32x4 v = ((const f32x4*)smem)[bl * 17 + q];
      const int cb = n0i + q * 4;
      const int l = cb >> 11, rr = cb & 2047;
      const int b = b0i + bl;
      ushort4v o;
#pragma unroll
      for (int cc = 0; cc < 4; ++cc) o[cc] = f2bf(fmaxf(v[cc] + tb1[cb + cc], 0.f));
      *(ushort4v*)(GBu + (long)l * 524288 + fta(b, rr, 64)) = o;
    }
  }
  grid_barrier(flags, ++bt);

  // ======== init2: tanh(GB @ tw2^T + tb2) -> (h0,c0),(h1,c1) ========
  if (slot < 8) {
    const int i_mt = slot & 1, i_ng = xcd * 4 + (slot >> 1);
    const int l = i_ng >> 4;
    f32x4 acc[4][2];
#pragma unroll
    for (int m = 0; m < 4; ++m)
#pragma unroll
      for (int n = 0; n < 2; ++n) acc[m][n] = (f32x4){0.f, 0.f, 0.f, 0.f};
    run_gemm(cGB + (long)l * 1048576 + (long)i_mt * 524288, cT2 + (long)i_ng * 262144, 16, nullptr,
             nullptr, 0, nullptr, nullptr, 16, smem, tid, wm, wn, lane, acc);
    store_lds_tile((float*)smem, acc, wm, wn, lane);
    __syncthreads();
    const int b0i = i_mt * 128, n0i = i_ng * 64;
    for (int i = tid; i < 2048; i += 256) {
      const int bl = i >> 4, q = i & 15;
      const f32x4 v = ((const f32x4*)smem)[bl * 17 + q];
      const int cb = n0i + q * 4;
      const int ll = cb >> 10, rr = cb & 1023;
      const int b = b0i + bl;
      if (rr < 512) {
        ushort4v o;
#pragma unroll
        for (int cc = 0; cc < 4; ++cc) o[cc] = f2bf(tanh_f(v[cc] + tb2[cb + cc]));
        *(ushort4v*)((ushort*)(ll ? cH1 : cH0) + fta(b, rr, 16)) = o;  // parity 0
      } else {
        f32x4 o;
#pragma unroll
        for (int cc = 0; cc < 4; ++cc) o[cc] = tanh_f(v[cc] + tb2[cb + cc]);
        *(f32x4*)((ll ? C1f : C0f) + b * 512 + (rr - 512)) = o;
      }
    }
  }
  grid_barrier(flags, ++bt);

  // ======== 40 decode steps, 2 phases each ========
  for (int t = 0; t < 40; ++t) {
    const int p = t & 1;

    // -------- phase 1: L0 gates || logits-halfA(t-1) || combine(t-2) --------
    if (slot < 8) {
      const int mt = slot & 1, ng = xcd * 4 + (slot >> 1);
      f32x4 acc[4][2];
#pragma unroll
      for (int m = 0; m < 4; ++m)
#pragma unroll
        for (int n = 0; n < 2; ++n) acc[m][n] = (f32x4){0.f, 0.f, 0.f, 0.f};
      const char* wB = cW0 + (long)ng * 147456;
      run_gemm(cH0 + (long)p * HPAR + (long)mt * HMT, wB, 4,
               cEF + (long)t * HPAR + (long)mt * HMT, wB + 65536, 4, cZF + (long)mt * 32768,
               wB + 131072, 9, smem, tid, wm, wn, lane, acc);
      store_lds_tile((float*)smem, acc, wm, wn, lane);
      __syncthreads();
      gates_pw_ft((const float*)smem, tid, mt * 128, ng * 16, bg0, C0f,
                  (ushort*)(cH0 + (long)(1 - p) * HPAR), H0F, nullptr, nullptr);
    } else if (slot < 18) {
      if (t >= 1) {
        const int jl = slot - 8;
        const int lmt = jl & 1, lng = xcd * 10 + (jl >> 1);
        f32x4 acc[4][2];
#pragma unroll
        for (int m = 0; m < 4; ++m)
#pragma unroll
          for (int n = 0; n < 2; ++n) acc[m][n] = (f32x4){0.f, 0.f, 0.f, 0.f};
        const char* wB = cWO + (long)lng * 81920;
        run_gemm(cHS + (long)((t - 1) & 1) * HPAR + (long)lmt * HMT, wB, 4,
                 cZF + (long)lmt * 32768, wB + 65536, 1, nullptr, nullptr, 5, smem, tid, wm, wn,
                 lane, acc);
        store_lds_tile((float*)smem, acc, wm, wn, lane);
        __syncthreads();
        const int pc = (t - 1) & 1;
        logits_epi((const float*)smem, tid, lmt * 128, lng, t, x, bout, MBf + pc * 20480,
                   SBf + pc * 20480, TGTf + pc * 256);
      }
    } else if (slot < 22) {
      if (t >= 2) {
        const int pc = (t - 2) & 1;
        const int rbase = xcd * 32 + (slot - 18) * 8 + w * 2;
        accO0 += combine_row(MBf + pc * 20480, SBf + pc * 20480, TGTf + pc * 256, rbase, lane);
        accO1 += combine_row(MBf + pc * 20480, SBf + pc * 20480, TGTf + pc * 256, rbase + 1, lane);
      }
    }
    grid_barrier(flags, ++bt);

    // -------- phase 2: L1 gates (+HS) || logits-halfB(t-1) --------
    if (slot < 8) {
      const int mt = slot & 1, ng = xcd * 4 + (slot >> 1);
      f32x4 acc[4][2];
#pragma unroll
      for (int m = 0; m < 4; ++m)
#pragma unroll
        for (int n = 0; n < 2; ++n) acc[m][n] = (f32x4){0.f, 0.f, 0.f, 0.f};
      const char* wB = cW1 + (long)ng * 131072;
      run_gemm(cH1 + (long)p * HPAR + (long)mt * HMT, wB, 4,
               cH0 + (long)(1 - p) * HPAR + (long)mt * HMT, wB + 65536, 4, nullptr, nullptr, 8,
               smem, tid, wm, wn, lane, acc);
      store_lds_tile((float*)smem, acc, wm, wn, lane);
      __syncthreads();
      gates_pw_ft((const float*)smem, tid, mt * 128, ng * 16, bg1, C1f,
                  (ushort*)(cH1 + (long)(1 - p) * HPAR), nullptr,
                  (ushort*)(cHS + (long)p * HPAR), H0F);
    } else if (slot < 18) {
      if (t >= 1) {
        const int jl = slot - 8;
        const int lmt = jl & 1, lng = xcd * 10 + 5 + (jl >> 1);
        f32x4 acc[4][2];
#pragma unroll
        for (int m = 0; m < 4; ++m)
#pragma unroll
          for (int n = 0; n < 2; ++n) acc[m][n] = (f32x4){0.f, 0.f, 0.f, 0.f};
        const char* wB = cWO + (long)lng * 81920;
        run_gemm(cHS + (long)((t - 1) & 1) * HPAR + (long)lmt * HMT, wB, 4,
                 cZF + (long)lmt * 32768, wB + 65536, 1, nullptr, nullptr, 5, smem, tid, wm, wn,
                 lane, acc);
        store_lds_tile((float*)smem, acc, wm, wn, lane);
        __syncthreads();
        const int pc = (t - 1) & 1;
        logits_epi((const float*)smem, tid, lmt * 128, lng, t, x, bout, MBf + pc * 20480,
                   SBf + pc * 20480, TGTf + pc * 256);
      }
    }
    grid_barrier(flags, ++bt);
  }

  // ======== final: combine(t'=38, parity 0) and write output ========
  if (slot >= 18 && slot < 22) {
    const int rbase = xcd * 32 + (slot - 18) * 8 + w * 2;
    accO0 += combine_row(MBf, SBf, TGTf, rbase, lane);
    accO1 += combine_row(MBf, SBf, TGTf, rbase + 1, lane);
    if (lane == 0) {
      out[rbase] = accO0;
      out[rbase + 1] = accO1;
    }
  }
}

// ---------------------------------------------------------------------------
extern "C" void kernel_launch(void* const* d_in, const int* in_sizes, int n_in, void* d_out,
                              int out_size, void* d_ws, size_t ws_size, hipStream_t stream) {
  const float* z = (const float*)d_in[0];
  const int* x = (const int*)d_in[1];
  const float* emb = (const float*)d_in[2];
  const float* Wg0 = (const float*)d_in[3];
  const float* bg0 = (const float*)d_in[4];
  const float* Wg1 = (const float*)d_in[5];
  const float* bg1 = (const float*)d_in[6];
  const float* Wout = (const float*)d_in[7];
  const float* bout = (const float*)d_in[8];
  const float* tw1 = (const float*)d_in[9];
  const float* tb1 = (const float*)d_in[10];
  const float* tw2 = (const float*)d_in[11];
  const float* tb2 = (const float*)d_in[12];
  unsigned char* ws = (unsigned char*)d_ws;
  float* out = (float*)d_out;

  hipMemsetAsync(ws, 0, 1024, stream);  // barrier flags
  prep_kernel<<<2048, 256, 0, stream>>>(Wg0, Wg1, Wout, emb, z, x, tw1, tw2, ws);
  decoder_main<<<256, 256, 0, stream>>>(x, bg0, bg1, bout, tb1, tb2, ws, out);
}

// Round 3
// 1125.110 us; speedup vs baseline: 3.5191x; 2.3213x over previous
//
#include <hip/hip_runtime.h>

// ============================================================================
// Persistent-kernel LSTM decoder, MI355X (gfx950) — round 3.
// vs round 2: (1) hierarchical grid barrier (per-block release flag, one
// aggregator block sweeps + publishes epoch, 1 poller/block) instead of a
// 65536-thread agent-scope spin storm; (2) phases merged via software
// pipelining: phase k = L0(t=k) || L1(t=k-1) || logits(t=k-2) || combine(k-3)
// -> 44 barriers instead of 82; (3) logits at 128x128 tiles; (4) cell state
// in registers (block-persistent); HS built from bf16 h0 (H0F dropped).
// ============================================================================

typedef unsigned int uint;
typedef unsigned short ushort;
typedef __attribute__((ext_vector_type(8))) __bf16 bf16x8;
typedef __attribute__((ext_vector_type(4))) float f32x4;
typedef __attribute__((ext_vector_type(4))) ushort ushort4v;
typedef __attribute__((ext_vector_type(8))) ushort ushort8v;

// ---- workspace byte offsets ----
#define OFF_FLAGS 0L         // 256 x u32 flags, epoch at +1024
#define OFF_W0    4096L      // [32 ng][36 kc] B-frag tiles, 2048x1152 bf16
#define OFF_W1    4722688L   // [32 ng][32 kc], 2048x1024
#define OFF_WO    8916992L   // [80 cg][20 kc], 5120x640 (vocab-padded)
#define OFF_EFT   15470592L  // [40 t][2 mt][16 kc] A-frag, gathered emb
#define OFF_ZFT   25956352L  // [2 mt][4 kc] A-frag of z
#define OFF_TW1   26021888L  // [64 ng][4 kc], 4096x128
#define OFF_TW2   27070464L  // [32 ng][64 kc], 2048x2048
#define OFF_GB    35459072L  // [2 l][2 mt][64 kc] A-frag relu hidden
#define OFF_H0    37556224L  // [2 par][2 mt][16 kc] A-frag h0
#define OFF_H1    38080512L  // [2 par] h1
#define OFF_HS    38604800L  // [2 par] h0+h1 (logits A)
#define OFF_C0    39129088L  // [256][512] f32
#define OFF_C1    39653376L  // [256][512] f32
#define OFF_MB    40177664L  // [2 par][256][40] f32
#define OFF_SB    40259584L  // [2 par][256][40] f32
#define OFF_TGT   40341504L  // [2 par][256] f32

#define HPAR 262144L  // bytes per parity of an A-frag [2mt][16kc] buffer
#define HMT  131072L  // bytes per mt
#define SLOT_G 24576  // gate ring slot: A 16KB | B 8KB
#define SLOT_L 32768  // logits ring slot: A 16KB | Blo 8KB | Bhi 8KB

__device__ __forceinline__ ushort f2bf(float f) {
  uint u = __float_as_uint(f);
  u = (u + 0x7fffu + ((u >> 16) & 1u)) >> 16;  // RNE
  return (ushort)u;
}
__device__ __forceinline__ float bf2f(ushort u) { return __uint_as_float(((uint)u) << 16); }
__device__ __forceinline__ float sigm(float v) { return 1.f / (1.f + __expf(-v)); }
__device__ __forceinline__ float tanh_f(float v) {
  float a = fabsf(v);
  float e = __expf(-2.f * a);
  return copysignf((1.f - e) / (1.f + e), v);
}
__device__ __forceinline__ f32x4 mfma16(bf16x8 a, bf16x8 b, f32x4 c) {
  return __builtin_amdgcn_mfma_f32_16x16x32_bf16(a, b, c, 0, 0, 0);
}

// A-fragment-tile element index for a [256 rows][K] matrix, KC = K/32.
// chunk = 128rows x 32k = 4096 elems: [r8(8)][kq(4)][row16(16)][k8(8)].
__device__ __forceinline__ long fta(int b, int k, int KC) {
  return ((long)(((b >> 7) & 1) * KC + (k >> 5)) << 12) +
         (((((b >> 4) & 7) << 2) + ((k >> 3) & 3)) << 7) + ((b & 15) << 3) + (k & 7);
}

__device__ __forceinline__ void gl_lds16(const char* g, char* l) {
  __builtin_amdgcn_global_load_lds((const __attribute__((address_space(1))) void*)g,
                                   (__attribute__((address_space(3))) void*)l, 16, 0, 0);
}

// ---- gate-config staging: 64-k section = A 16KB + B 8KB (6 loads/thread) ----
__device__ __forceinline__ void stage_g(const char* A, const char* B, char* slot, int o) {
#pragma unroll
  for (int i = 0; i < 4; ++i) gl_lds16(A + i * 4096 + o, slot + i * 4096 + o);
#pragma unroll
  for (int i = 0; i < 2; ++i) gl_lds16(B + i * 4096 + o, slot + 16384 + i * 4096 + o);
}
// ---- logits-config: A 16KB + Blo 8KB + Bhi 8KB (8 loads/thread) ----
__device__ __forceinline__ void stage_l(const char* A, const char* Blo, const char* Bhi,
                                        char* slot, int o) {
#pragma unroll
  for (int i = 0; i < 4; ++i) gl_lds16(A + i * 4096 + o, slot + i * 4096 + o);
#pragma unroll
  for (int i = 0; i < 2; ++i) gl_lds16(Blo + i * 4096 + o, slot + 16384 + i * 4096 + o);
#pragma unroll
  for (int i = 0; i < 2; ++i) gl_lds16(Bhi + i * 4096 + o, slot + 24576 + i * 4096 + o);
}

__device__ __forceinline__ const char* aseg(int s, const char* A0, int n0, const char* A1,
                                            int n1, const char* A2) {
  if (s < n0) return A0 + (long)s * 16384;
  if (s < n0 + n1) return A1 + (long)(s - n0) * 16384;
  return A2 + (long)(s - n0 - n1) * 16384;
}

// 128x64 tile GEMM; ring-3 staging; raw s_barrier + vmcnt(6) (never 0 mid-loop)
__device__ __forceinline__ void run_gemm_g(const char* A0, int n0, const char* A1, int n1,
                                           const char* A2, const char* Bs, int S, char* smem,
                                           int tid, int wm, int wn, int lane,
                                           f32x4 (&acc)[4][2]) {
  const int o = tid * 16;
  stage_g(aseg(0, A0, n0, A1, n1, A2), Bs, smem, o);
  if (S > 1) stage_g(aseg(1, A0, n0, A1, n1, A2), Bs + 8192, smem + SLOT_G, o);
  const int ab = wm * 4096 + lane * 16;
  const int bb = 16384 + wn * 2048 + lane * 16;
  for (int s = 0; s < S; ++s) {
    if (s + 1 < S)
      __builtin_amdgcn_s_waitcnt(0x0F76);  // vmcnt(6)
    else
      __builtin_amdgcn_s_waitcnt(0x0F70);  // vmcnt(0) tail
    __builtin_amdgcn_s_barrier();
    char* sb = smem + (s % 3) * SLOT_G;
    if (s + 2 < S)
      stage_g(aseg(s + 2, A0, n0, A1, n1, A2), Bs + (long)(s + 2) * 8192,
              smem + ((s + 2) % 3) * SLOT_G, o);
#pragma unroll
    for (int c = 0; c < 2; ++c) {
      const char* ap = sb + c * 8192 + ab;
      const char* bp = sb + c * 4096 + bb;
      bf16x8 Af0 = *(const bf16x8*)(ap);
      bf16x8 Af1 = *(const bf16x8*)(ap + 1024);
      bf16x8 Af2 = *(const bf16x8*)(ap + 2048);
      bf16x8 Af3 = *(const bf16x8*)(ap + 3072);
      bf16x8 Bf0 = *(const bf16x8*)(bp);
      bf16x8 Bf1 = *(const bf16x8*)(bp + 1024);
      acc[0][0] = mfma16(Af0, Bf0, acc[0][0]);
      acc[0][1] = mfma16(Af0, Bf1, acc[0][1]);
      acc[1][0] = mfma16(Af1, Bf0, acc[1][0]);
      acc[1][1] = mfma16(Af1, Bf1, acc[1][1]);
      acc[2][0] = mfma16(Af2, Bf0, acc[2][0]);
      acc[2][1] = mfma16(Af2, Bf1, acc[2][1]);
      acc[3][0] = mfma16(Af3, Bf0, acc[3][0]);
      acc[3][1] = mfma16(Af3, Bf1, acc[3][1]);
    }
  }
  __syncthreads();
}

// 128x128 tile GEMM (logits): wave = 64x64 (acc[4][4]); wn picks Blo/Bhi
__device__ __forceinline__ void run_gemm_l(const char* A0, int n0, const char* A1,
                                           const char* Blo, const char* Bhi, int S, char* smem,
                                           int tid, int wm, int wn, int lane,
                                           f32x4 (&acc)[4][4]) {
  const int o = tid * 16;
  stage_l(aseg(0, A0, n0, A1, 8, A1), Blo, Bhi, smem, o);
  stage_l(aseg(1, A0, n0, A1, 8, A1), Blo + 8192, Bhi + 8192, smem + SLOT_L, o);
  const int ab = wm * 4096 + lane * 16;
  const int bb = 16384 + wn * 8192 + lane * 16;
  for (int s = 0; s < S; ++s) {
    if (s + 1 < S)
      __builtin_amdgcn_s_waitcnt(0x0F78);  // vmcnt(8)
    else
      __builtin_amdgcn_s_waitcnt(0x0F70);
    __builtin_amdgcn_s_barrier();
    char* sb = smem + (s % 3) * SLOT_L;
    if (s + 2 < S)
      stage_l(aseg(s + 2, A0, n0, A1, 8, A1), Blo + (long)(s + 2) * 8192,
              Bhi + (long)(s + 2) * 8192, smem + ((s + 2) % 3) * SLOT_L, o);
#pragma unroll
    for (int c = 0; c < 2; ++c) {
      const char* ap = sb + c * 8192 + ab;
      const char* bp = sb + c * 4096 + bb;
      bf16x8 Af[4], Bf[4];
#pragma unroll
      for (int m = 0; m < 4; ++m) Af[m] = *(const bf16x8*)(ap + m * 1024);
#pragma unroll
      for (int n = 0; n < 4; ++n) Bf[n] = *(const bf16x8*)(bp + n * 1024);
#pragma unroll
      for (int m = 0; m < 4; ++m)
#pragma unroll
        for (int n = 0; n < 4; ++n) acc[m][n] = mfma16(Af[m], Bf[n], acc[m][n]);
    }
  }
  __syncthreads();
}

// C/D layout: col = lane&15, row = (lane>>4)*4 + reg
__device__ __forceinline__ void store_lds_tile(float* lds, f32x4 (&acc)[4][2], int wm, int wn,
                                               int lane) {
  const int l15 = lane & 15, lq = lane >> 4;
#pragma unroll
  for (int m = 0; m < 4; ++m)
#pragma unroll
    for (int n = 0; n < 2; ++n)
#pragma unroll
      for (int r = 0; r < 4; ++r)
        lds[(wm * 64 + m * 16 + lq * 4 + r) * 68 + (wn * 32 + n * 16 + l15)] = acc[m][n][r];
}
__device__ __forceinline__ void store_lds_tile128(float* lds, f32x4 (&acc)[4][4], int wm, int wn,
                                                  int lane) {
  const int l15 = lane & 15, lq = lane >> 4;
#pragma unroll
  for (int m = 0; m < 4; ++m)
#pragma unroll
    for (int n = 0; n < 4; ++n)
#pragma unroll
      for (int r = 0; r < 4; ++r)
        lds[(wm * 64 + m * 16 + lq * 4 + r) * 132 + (wn * 64 + n * 16 + l15)] = acc[m][n][r];
}

// hierarchical grid barrier: per-block release flag; aggregator block sweeps
// all flags (256 pollers) and publishes epoch; others poll epoch with 1 lane.
__device__ __forceinline__ void grid_barrier3(uint* flags, uint* epoch, uint ph, bool isAgg) {
  __syncthreads();
  if (threadIdx.x == 0)
    __hip_atomic_store(&flags[blockIdx.x], ph, __ATOMIC_RELEASE, __HIP_MEMORY_SCOPE_AGENT);
  if (isAgg) {
    uint v = __hip_atomic_load(&flags[threadIdx.x], __ATOMIC_RELAXED, __HIP_MEMORY_SCOPE_AGENT);
    while (v < ph) {
      __builtin_amdgcn_s_sleep(2);
      v = __hip_atomic_load(&flags[threadIdx.x], __ATOMIC_RELAXED, __HIP_MEMORY_SCOPE_AGENT);
    }
    __syncthreads();
    if (threadIdx.x == 0) {
      __builtin_amdgcn_fence(__ATOMIC_ACQUIRE, "agent");
      __hip_atomic_store(epoch, ph, __ATOMIC_RELEASE, __HIP_MEMORY_SCOPE_AGENT);
    }
  } else if (threadIdx.x == 0) {
    uint v = __hip_atomic_load(epoch, __ATOMIC_RELAXED, __HIP_MEMORY_SCOPE_AGENT);
    while (v < ph) {
      __builtin_amdgcn_s_sleep(2);
      v = __hip_atomic_load(epoch, __ATOMIC_RELAXED, __HIP_MEMORY_SCOPE_AGENT);
    }
    __builtin_amdgcn_fence(__ATOMIC_ACQUIRE, "agent");
  }
  __syncthreads();
}

// LSTM gate pointwise; tile [128 b][16 d x 4 g] f32; C in registers.
template <bool WHS>
__device__ __forceinline__ void gates_pw3(const float* tile, int tid, int b0, int d0,
                                          const float* __restrict__ bg, float (&cp)[8],
                                          ushort* __restrict__ hw,
                                          const ushort* __restrict__ h0r,
                                          ushort* __restrict__ hs) {
#pragma unroll
  for (int j = 0; j < 8; ++j) {
    const int i = tid + j * 256;
    const int bl = i >> 4, dq = i & 15;
    const f32x4 g = ((const f32x4*)tile)[bl * 17 + dq];
    const int d = d0 + dq, b = b0 + bl;
    const float gi = g[0] + bg[d];
    const float gf = g[1] + bg[512 + d];
    const float go = g[2] + bg[1024 + d];
    const float gc = g[3] + bg[1536 + d];
    const float ii = sigm(gi), ff = sigm(gf), oo = sigm(go), cn = tanh_f(gc);
    const float c = ff * cp[j] + ii * cn;
    cp[j] = c;
    const float h = oo * tanh_f(c);
    const long ft = fta(b, d, 16);
    hw[ft] = f2bf(h);
    if (WHS) hs[ft] = f2bf(h + bf2f(h0r[ft]));
  }
}

__device__ __forceinline__ float combine_row3(const float* __restrict__ MBc,
                                              const float* __restrict__ SBc,
                                              const float* __restrict__ TGTc, int r, int lane) {
  float M = lane < 40 ? MBc[r * 40 + lane] : -3.0e38f;
  float S = lane < 40 ? SBc[r * 40 + lane] : 0.f;
#pragma unroll
  for (int off = 32; off > 0; off >>= 1) {
    const float Mo = __shfl_xor(M, off, 64);
    const float So = __shfl_xor(S, off, 64);
    const float Mn = fmaxf(M, Mo);
    S = S * __expf(M - Mn) + So * __expf(Mo - Mn);
    M = Mn;
  }
  return TGTc[r] - (M + __logf(S));
}

// ---------------------------------------------------------------------------
__device__ __forceinline__ void cv8(ushort8v& o, const float* s) {
  const f32x4 a = *(const f32x4*)s, b = *(const f32x4*)(s + 4);
#pragma unroll
  for (int j = 0; j < 4; ++j) o[j] = f2bf(a[j]);
#pragma unroll
  for (int j = 0; j < 4; ++j) o[4 + j] = f2bf(b[j]);
}
__device__ __forceinline__ void bft8(ushort* dst, int col, int kg, int KC, const float* src) {
  ushort8v o;
  cv8(o, src);
  *(ushort8v*)(dst + ((long)((col >> 6) * KC + (kg >> 2)) << 11) +
               (((((col >> 4) & 3) << 2) + (kg & 3)) << 7) + ((col & 15) << 3)) = o;
}
__device__ __forceinline__ void bft8z(ushort* dst, int col, int kg, int KC) {
  ushort8v o = (ushort8v)0;
  *(ushort8v*)(dst + ((long)((col >> 6) * KC + (kg >> 2)) << 11) +
               (((((col >> 4) & 3) << 2) + (kg & 3)) << 7) + ((col & 15) << 3)) = o;
}
__device__ __forceinline__ void aft8(ushort* dst, int b, int kg, int KC, const float* src) {
  ushort8v o;
  cv8(o, src);
  *(ushort8v*)(dst + ((long)(((b >> 7) & 1) * KC + (kg >> 2)) << 12) +
               (((((b >> 4) & 7) << 2) + (kg & 3)) << 7) + ((b & 15) << 3)) = o;
}

__global__ void __launch_bounds__(256) prep_kernel(
    const float* __restrict__ Wg0, const float* __restrict__ Wg1, const float* __restrict__ Wout,
    const float* __restrict__ emb, const float* __restrict__ z, const int* __restrict__ x,
    const float* __restrict__ tw1, const float* __restrict__ tw2, unsigned char* __restrict__ ws) {
  ushort* W0 = (ushort*)(ws + OFF_W0);
  ushort* W1 = (ushort*)(ws + OFF_W1);
  ushort* WO = (ushort*)(ws + OFF_WO);
  ushort* EF = (ushort*)(ws + OFF_EFT);
  ushort* ZF = (ushort*)(ws + OFF_ZFT);
  ushort* T1 = (ushort*)(ws + OFF_TW1);
  ushort* T2 = (ushort*)(ws + OFF_TW2);
  const long N0 = 294912, N1 = 262144, N2 = 409600, N3 = 655360, N4 = 4096, N5 = 65536,
             N6 = 524288;
  const long total = N0 + N1 + N2 + N3 + N4 + N5 + N6;
  for (long idx = (long)blockIdx.x * 256 + threadIdx.x; idx < total;
       idx += (long)gridDim.x * 256) {
    long j = idx;
    if (j < N0) {  // W0: gate-interleaved col r=d*4+g
      const int col = (int)(j / 144), kg = (int)(j - (long)col * 144);
      bft8(W0, col, kg, 36, Wg0 + (long)((col & 3) * 512 + (col >> 2)) * 1152 + kg * 8);
    } else if ((j -= N0) < N1) {
      const int col = (int)(j >> 7), kg = (int)(j & 127);
      bft8(W1, col, kg, 32, Wg1 + (long)((col & 3) * 512 + (col >> 2)) * 1024 + kg * 8);
    } else if ((j -= N1) < N2) {
      const int col = (int)(j / 80), kg = (int)(j - (long)col * 80);
      if (col < 5000)
        bft8(WO, col, kg, 20, Wout + (long)col * 640 + kg * 8);
      else
        bft8z(WO, col, kg, 20);
    } else if ((j -= N2) < N3) {  // emb gather, all t
      const int t = (int)(j >> 14), r = (int)(j & 16383);
      const int b = r >> 6, kg = r & 63;
      aft8(EF + (long)t * 131072, b, kg, 16, emb + (long)x[b * 40 + t] * 512 + kg * 8);
    } else if ((j -= N3) < N4) {
      const int b = (int)(j >> 4), kg = (int)(j & 15);
      aft8(ZF, b, kg, 4, z + b * 128 + kg * 8);
    } else if ((j -= N4) < N5) {
      const int col = (int)(j >> 4), kg = (int)(j & 15);
      bft8(T1, col, kg, 4, tw1 + (long)(col >> 11) * 262144 + (long)(col & 2047) * 128 + kg * 8);
    } else {
      j -= N5;
      const int col = (int)(j >> 8), kg = (int)(j & 255);
      bft8(T2, col, kg, 64, tw2 + (long)(col >> 10) * 2097152 + (long)(col & 1023) * 2048 + kg * 8);
    }
  }
}

// ---------------------------------------------------------------------------
__global__ void __launch_bounds__(256) decoder_main(
    const int* __restrict__ x, const float* __restrict__ bg0, const float* __restrict__ bg1,
    const float* __restrict__ bout, const float* __restrict__ tb1, const float* __restrict__ tb2,
    unsigned char* __restrict__ ws, float* __restrict__ out) {
  __shared__ __align__(16) char smem[98304];  // logits ring 3x32KB; others smaller

  uint* flags = (uint*)(ws + OFF_FLAGS);
  uint* epoch = (uint*)(ws + OFF_FLAGS + 1024);
  const char* cW0 = (const char*)(ws + OFF_W0);
  const char* cW1 = (const char*)(ws + OFF_W1);
  const char* cWO = (const char*)(ws + OFF_WO);
  const char* cEF = (const char*)(ws + OFF_EFT);
  const char* cZF = (const char*)(ws + OFF_ZFT);
  const char* cT1 = (const char*)(ws + OFF_TW1);
  const char* cT2 = (const char*)(ws + OFF_TW2);
  char* cGB = (char*)(ws + OFF_GB);
  char* cH0 = (char*)(ws + OFF_H0);
  char* cH1 = (char*)(ws + OFF_H1);
  char* cHS = (char*)(ws + OFF_HS);
  float* C0f = (float*)(ws + OFF_C0);
  float* C1f = (float*)(ws + OFF_C1);
  float* MBf = (float*)(ws + OFF_MB);
  float* SBf = (float*)(ws + OFF_SB);
  float* TGTf = (float*)(ws + OFF_TGT);

  const int bid = blockIdx.x;
  const int tid = threadIdx.x;
  const int lane = tid & 63;
  const int w = tid >> 6;
  const int wm = w & 1, wn = w >> 1;
  const int xcd = bid & 7;    // round-robin block->XCD heuristic
  const int slot = bid >> 3;  // 0..31 within XCD
  const bool isAgg = (bid == 240);  // xcd 0, slot 30 (idle class)

  uint ph = 0;
  float cpriv[8];
  float accO0 = 0.f, accO1 = 0.f;

  // ======== init1: relu(z @ tw1^T + tb1) -> GB ========
  if (slot < 16) {
    const int i_mt = slot & 1, i_ng = xcd * 8 + (slot >> 1);
    f32x4 acc[4][2];
#pragma unroll
    for (int m = 0; m < 4; ++m)
#pragma unroll
      for (int n = 0; n < 2; ++n) acc[m][n] = (f32x4){0.f, 0.f, 0.f, 0.f};
    run_gemm_g(cZF + (long)i_mt * 32768, 2, nullptr, 0, nullptr, cT1 + (long)i_ng * 16384, 2,
               smem, tid, wm, wn, lane, acc);
    store_lds_tile((float*)smem, acc, wm, wn, lane);
    __syncthreads();
    const int b0i = i_mt * 128, n0i = i_ng * 64;
    ushort* GBu = (ushort*)cGB;
    for (int i = tid; i < 2048; i += 256) {
      const int bl = i >> 4, q = i & 15;
      const f32x4 v = ((const f32x4*)smem)[bl * 17 + q];
      const int cb = n0i + q * 4;
      const int l = cb >> 11, rr = cb & 2047;
      ushort4v o;
#pragma unroll
      for (int cc = 0; cc < 4; ++cc) o[cc] = f2bf(fmaxf(v[cc] + tb1[cb + cc], 0.f));
      *(ushort4v*)(GBu + (long)l * 524288 + fta(b0i + bl, rr, 64)) = o;
    }
  }
  grid_barrier3(flags, epoch, ++ph, isAgg);

  // ======== init2: tanh(GB @ tw2^T + tb2) -> (h parity1, C) ========
  if (slot < 8) {
    const int i_mt = slot & 1, i_ng = xcd * 4 + (slot >> 1);
    const int l = i_ng >> 4;
    f32x4 acc[4][2];
#pragma unroll
    for (int m = 0; m < 4; ++m)
#pragma unroll
      for (int n = 0; n < 2; ++n) acc[m][n] = (f32x4){0.f, 0.f, 0.f, 0.f};
    run_gemm_g(cGB + (long)l * 1048576 + (long)i_mt * 524288, 32, nullptr, 0, nullptr,
               cT2 + (long)i_ng * 262144, 32, smem, tid, wm, wn, lane, acc);
    store_lds_tile((float*)smem, acc, wm, wn, lane);
    __syncthreads();
    const int b0i = i_mt * 128, n0i = i_ng * 64;
    for (int i = tid; i < 2048; i += 256) {
      const int bl = i >> 4, q = i & 15;
      const f32x4 v = ((const f32x4*)smem)[bl * 17 + q];
      const int cb = n0i + q * 4;
      const int ll = cb >> 10, rr = cb & 1023;
      const int b = b0i + bl;
      if (rr < 512) {  // initial h at parity 1
        ushort4v o;
#pragma unroll
        for (int cc = 0; cc < 4; ++cc) o[cc] = f2bf(tanh_f(v[cc] + tb2[cb + cc]));
        *(ushort4v*)((ushort*)((ll ? cH1 : cH0) + HPAR) + fta(b, rr, 16)) = o;
      } else {
        f32x4 o;
#pragma unroll
        for (int cc = 0; cc < 4; ++cc) o[cc] = tanh_f(v[cc] + tb2[cb + cc]);
        *(f32x4*)((ll ? C1f : C0f) + b * 512 + (rr - 512)) = o;
      }
    }
  }
  grid_barrier3(flags, epoch, ++ph, isAgg);

  // block-persistent roles + C tile -> registers
  const int mt = slot & 1;
  const int gng = xcd * 4 + ((slot & 7) >> 1);  // for G0/G1
  if (slot < 16) {
    const float* Cf = (slot < 8) ? C0f : C1f;
#pragma unroll
    for (int j = 0; j < 8; ++j) {
      const int i = tid + j * 256;
      cpriv[j] = Cf[(mt * 128 + (i >> 4)) * 512 + gng * 16 + (i & 15)];
    }
  }

  // ======== 42 pipelined phases ========
  for (int k = 0; k < 42; ++k) {
    if (slot < 8) {  // ---- G0: L0 gates, t = k ----
      if (k <= 39) {
        f32x4 acc[4][2];
#pragma unroll
        for (int m = 0; m < 4; ++m)
#pragma unroll
          for (int n = 0; n < 2; ++n) acc[m][n] = (f32x4){0.f, 0.f, 0.f, 0.f};
        run_gemm_g(cH0 + (long)((k - 1) & 1) * HPAR + (long)mt * HMT, 8,
                   cEF + (long)k * HPAR + (long)mt * HMT, 8, cZF + (long)mt * 32768,
                   cW0 + (long)gng * 147456, 18, smem, tid, wm, wn, lane, acc);
        store_lds_tile((float*)smem, acc, wm, wn, lane);
        __syncthreads();
        gates_pw3<false>((const float*)smem, tid, mt * 128, gng * 16, bg0, cpriv,
                         (ushort*)(cH0 + (long)(k & 1) * HPAR), nullptr, nullptr);
      }
    } else if (slot < 16) {  // ---- G1: L1 gates, t = k-1 (+HS) ----
      if (k >= 1 && k <= 40) {
        f32x4 acc[4][2];
#pragma unroll
        for (int m = 0; m < 4; ++m)
#pragma unroll
          for (int n = 0; n < 2; ++n) acc[m][n] = (f32x4){0.f, 0.f, 0.f, 0.f};
        run_gemm_g(cH1 + (long)(k & 1) * HPAR + (long)mt * HMT, 8,
                   cH0 + (long)((k - 1) & 1) * HPAR + (long)mt * HMT, 8, nullptr,
                   cW1 + (long)gng * 131072, 16, smem, tid, wm, wn, lane, acc);
        store_lds_tile((float*)smem, acc, wm, wn, lane);
        __syncthreads();
        gates_pw3<true>((const float*)smem, tid, mt * 128, gng * 16, bg1, cpriv,
                        (ushort*)(cH1 + (long)((k - 1) & 1) * HPAR),
                        (const ushort*)(cH0 + (long)((k - 1) & 1) * HPAR),
                        (ushort*)(cHS + (long)((k - 1) & 1) * HPAR));
      }
    } else if (slot < 26) {  // ---- logits, t' = k-2, target x[.,k-1] ----
      if (k >= 2 && k <= 40) {
        const int ls = slot - 16, lmt = ls & 1, lng = xcd * 5 + (ls >> 1);
        f32x4 acc[4][4];
#pragma unroll
        for (int m = 0; m < 4; ++m)
#pragma unroll
          for (int n = 0; n < 4; ++n) acc[m][n] = (f32x4){0.f, 0.f, 0.f, 0.f};
        run_gemm_l(cHS + (long)(k & 1) * HPAR + (long)lmt * HMT, 8, cZF + (long)lmt * 32768,
                   cWO + (long)(2 * lng) * 81920, cWO + (long)(2 * lng + 1) * 81920, 10, smem,
                   tid, wm, wn, lane, acc);
        store_lds_tile128((float*)smem, acc, wm, wn, lane);
        __syncthreads();
        const int row = tid >> 1, half = tid & 1, b = lmt * 128 + row;
        const int n0 = lng * 128 + half * 64;
        const int xt = x[b * 40 + (k - 1)];
        const float* rowp = (const float*)smem + row * 132 + half * 64;
        float mx = -3.0e38f, tv = 0.f;
        for (int j = 0; j < 64; j += 4) {
          const f32x4 v = *(const f32x4*)(rowp + j);
#pragma unroll
          for (int cc = 0; cc < 4; ++cc) {
            const int col = n0 + j + cc;
            if (col < 5000) {
              const float val = v[cc] + bout[col];
              mx = fmaxf(mx, val);
              if (col == xt) tv = val;
            }
          }
        }
        float sa = 0.f;
        for (int j = 0; j < 64; j += 4) {
          const f32x4 v = *(const f32x4*)(rowp + j);
#pragma unroll
          for (int cc = 0; cc < 4; ++cc) {
            const int col = n0 + j + cc;
            if (col < 5000) sa += __expf(v[cc] + bout[col] - mx);
          }
        }
        const float mo = __shfl_xor(mx, 1, 64), so = __shfl_xor(sa, 1, 64),
                    to = __shfl_xor(tv, 1, 64);
        const float Mn = fmaxf(mx, mo);
        const float Sm = sa * __expf(mx - Mn) + so * __expf(mo - Mn);
        const int par = k & 1;
        if (half == 0) {
          MBf[par * 10240 + b * 40 + lng] = Mn;
          SBf[par * 10240 + b * 40 + lng] = Sm;
          if (xt >= lng * 128 && xt < lng * 128 + 128) TGTf[par * 256 + b] = tv + to;
        }
      }
    } else if (slot < 30) {  // ---- combine, logits of phase k-1 ----
      if (k >= 3 && k <= 41) {
        const int par = (k - 1) & 1;
        const int r0 = (xcd * 4 + (slot - 26)) * 8 + w * 2;
        accO0 += combine_row3(MBf + par * 10240, SBf + par * 10240, TGTf + par * 256, r0, lane);
        accO1 +=
            combine_row3(MBf + par * 10240, SBf + par * 10240, TGTf + par * 256, r0 + 1, lane);
      }
    }
    grid_barrier3(flags, epoch, ++ph, isAgg);
  }

  if (slot >= 26 && slot < 30 && lane == 0) {
    const int r0 = (xcd * 4 + (slot - 26)) * 8 + w * 2;
    out[r0] = accO0;
    out[r0 + 1] = accO1;
  }
}

// ---------------------------------------------------------------------------
extern "C" void kernel_launch(void* const* d_in, const int* in_sizes, int n_in, void* d_out,
                              int out_size, void* d_ws, size_t ws_size, hipStream_t stream) {
  const float* z = (const float*)d_in[0];
  const int* x = (const int*)d_in[1];
  const float* emb = (const float*)d_in[2];
  const float* Wg0 = (const float*)d_in[3];
  const float* bg0 = (const float*)d_in[4];
  const float* Wg1 = (const float*)d_in[5];
  const float* bg1 = (const float*)d_in[6];
  const float* Wout = (const float*)d_in[7];
  const float* bout = (const float*)d_in[8];
  const float* tw1 = (const float*)d_in[9];
  const float* tb1 = (const float*)d_in[10];
  const float* tw2 = (const float*)d_in[11];
  const float* tb2 = (const float*)d_in[12];
  unsigned char* ws = (unsigned char*)d_ws;
  float* out = (float*)d_out;

  hipMemsetAsync(ws, 0, 4096, stream);  // flags + epoch
  prep_kernel<<<2048, 256, 0, stream>>>(Wg0, Wg1, Wout, emb, z, x, tw1, tw2, ws);
  decoder_main<<<256, 256, 0, stream>>>(x, bg0, bg1, bout, tb1, tb2, ws, out);
}

// Round 4
// 927.256 us; speedup vs baseline: 4.2700x; 1.2134x over previous
//
#include <hip/hip_runtime.h>

// ============================================================================
// Persistent-kernel LSTM decoder, MI355X (gfx950) — round 4.
// vs round 3: NO agent-scope fences anywhere (they emit buffer_wbl2/buffer_inv
// = full L2 writeback/invalidate per barrier, ~20us/phase and they wipe the
// weight working set out of L2). Instead, all mutable cross-block data flows
// through the coherence point with sc0|sc1 accesses: relaxed agent atomics for
// scalars, global_load_lds aux=0x11 (SC0|SC1) for LDS staging. Weights stay
// L2-resident. Barrier = relaxed flag store (ordered by the vmcnt(0) that
// __syncthreads already emits) + hierarchical aggregation + relaxed polls.
// ============================================================================

typedef unsigned int uint;
typedef unsigned short ushort;
typedef unsigned long long u64;
typedef __attribute__((ext_vector_type(8))) __bf16 bf16x8;
typedef __attribute__((ext_vector_type(4))) float f32x4;
typedef __attribute__((ext_vector_type(4))) ushort ushort4v;
typedef __attribute__((ext_vector_type(8))) ushort ushort8v;

#define AUXC 0x11  // CPol SC0 (bit0) | SC1 (bit4): coherent, bypass L1/L2

// ---- workspace byte offsets ----
#define OFF_FLAGS 0L         // 256 x u32 flags, epoch at +1024
#define OFF_W0    4096L      // [32 ng][36 kc] B-frag tiles, 2048x1152 bf16
#define OFF_W1    4722688L   // [32 ng][32 kc], 2048x1024
#define OFF_WO    8916992L   // [80 cg][20 kc], 5120x640 (vocab-padded)
#define OFF_EFT   15470592L  // [40 t][2 mt][16 kc] A-frag, gathered emb
#define OFF_ZFT   25956352L  // [2 mt][4 kc] A-frag of z
#define OFF_TW1   26021888L  // [64 ng][4 kc], 4096x128
#define OFF_TW2   27070464L  // [32 ng][64 kc], 2048x2048
#define OFF_GB    35459072L  // [2 l][2 mt][64 kc] A-frag relu hidden
#define OFF_H0    37556224L  // [2 par][2 mt][16 kc] A-frag h0
#define OFF_H1    38080512L  // [2 par] h1
#define OFF_HS    38604800L  // [2 par] h0+h1 (logits A)
#define OFF_C0    39129088L  // [256][512] f32
#define OFF_C1    39653376L  // [256][512] f32
#define OFF_MB    40177664L  // [2 par][256][40] f32
#define OFF_SB    40259584L  // [2 par][256][40] f32
#define OFF_TGT   40341504L  // [2 par][256] f32

#define HPAR 262144L  // bytes per parity of an A-frag [2mt][16kc] buffer
#define HMT  131072L  // bytes per mt
#define SLOT_G 24576  // gate ring slot: A 16KB | B 8KB
#define SLOT_L 32768  // logits ring slot: A 16KB | Blo 8KB | Bhi 8KB

// ---- relaxed agent-scope (coherence-point) scalar access helpers ----
__device__ __forceinline__ uint ald32(const uint* p) {
  return __hip_atomic_load(p, __ATOMIC_RELAXED, __HIP_MEMORY_SCOPE_AGENT);
}
__device__ __forceinline__ void ast32(uint* p, uint v) {
  __hip_atomic_store(p, v, __ATOMIC_RELAXED, __HIP_MEMORY_SCOPE_AGENT);
}
__device__ __forceinline__ float aldf(const float* p) {
  return __hip_atomic_load(p, __ATOMIC_RELAXED, __HIP_MEMORY_SCOPE_AGENT);
}
__device__ __forceinline__ void astf(float* p, float v) {
  __hip_atomic_store(p, v, __ATOMIC_RELAXED, __HIP_MEMORY_SCOPE_AGENT);
}
__device__ __forceinline__ void ast64(u64* p, u64 v) {
  __hip_atomic_store(p, v, __ATOMIC_RELAXED, __HIP_MEMORY_SCOPE_AGENT);
}

__device__ __forceinline__ ushort f2bf(float f) {
  uint u = __float_as_uint(f);
  u = (u + 0x7fffu + ((u >> 16) & 1u)) >> 16;  // RNE
  return (ushort)u;
}
__device__ __forceinline__ float bf2f(ushort u) { return __uint_as_float(((uint)u) << 16); }
__device__ __forceinline__ float sigm(float v) { return 1.f / (1.f + __expf(-v)); }
__device__ __forceinline__ float tanh_f(float v) {
  float a = fabsf(v);
  float e = __expf(-2.f * a);
  return copysignf((1.f - e) / (1.f + e), v);
}
__device__ __forceinline__ f32x4 mfma16(bf16x8 a, bf16x8 b, f32x4 c) {
  return __builtin_amdgcn_mfma_f32_16x16x32_bf16(a, b, c, 0, 0, 0);
}

// A-fragment-tile element index for a [256 rows][K] matrix, KC = K/32.
// chunk = 128rows x 32k = 4096 elems: [r8(8)][kq(4)][row16(16)][k8(8)].
__device__ __forceinline__ long fta(int b, int k, int KC) {
  return ((long)(((b >> 7) & 1) * KC + (k >> 5)) << 12) +
         (((((b >> 4) & 7) << 2) + ((k >> 3) & 3)) << 7) + ((b & 15) << 3) + (k & 7);
}

template <int AUX>
__device__ __forceinline__ void gl_lds16(const char* g, char* l) {
  __builtin_amdgcn_global_load_lds((const __attribute__((address_space(1))) void*)g,
                                   (__attribute__((address_space(3))) void*)l, 16, 0, AUX);
}

// ---- gate-config staging: 64-k section = A 16KB (aux AXA) + B 8KB (cached) ----
template <int AXA>
__device__ __forceinline__ void stage_g(const char* A, const char* B, char* slot, int o) {
#pragma unroll
  for (int i = 0; i < 4; ++i) gl_lds16<AXA>(A + i * 4096 + o, slot + i * 4096 + o);
#pragma unroll
  for (int i = 0; i < 2; ++i) gl_lds16<0>(B + i * 4096 + o, slot + 16384 + i * 4096 + o);
}
template <int AX0, int AX1, int AX2>
__device__ __forceinline__ void stg_disp_g(int s, const char* A0, int n0, const char* A1, int n1,
                                           const char* A2, const char* Bs, char* dst, int o) {
  const char* Bp = Bs + (long)s * 8192;
  if (s < n0)
    stage_g<AX0>(A0 + (long)s * 16384, Bp, dst, o);
  else if (s < n0 + n1)
    stage_g<AX1>(A1 + (long)(s - n0) * 16384, Bp, dst, o);
  else
    stage_g<AX2>(A2 + (long)(s - n0 - n1) * 16384, Bp, dst, o);
}

// ---- logits-config: A 16KB (aux AXA) + Blo 8KB + Bhi 8KB (cached) ----
template <int AXA>
__device__ __forceinline__ void stage_l(const char* A, const char* Blo, const char* Bhi,
                                        char* slot, int o) {
#pragma unroll
  for (int i = 0; i < 4; ++i) gl_lds16<AXA>(A + i * 4096 + o, slot + i * 4096 + o);
#pragma unroll
  for (int i = 0; i < 2; ++i) gl_lds16<0>(Blo + i * 4096 + o, slot + 16384 + i * 4096 + o);
#pragma unroll
  for (int i = 0; i < 2; ++i) gl_lds16<0>(Bhi + i * 4096 + o, slot + 24576 + i * 4096 + o);
}
template <int AX0, int AX1>
__device__ __forceinline__ void stg_disp_l(int s, const char* A0, int n0, const char* A1,
                                           const char* Blo, const char* Bhi, char* dst, int o) {
  const char* bl = Blo + (long)s * 8192;
  const char* bh = Bhi + (long)s * 8192;
  if (s < n0)
    stage_l<AX0>(A0 + (long)s * 16384, bl, bh, dst, o);
  else
    stage_l<AX1>(A1 + (long)(s - n0) * 16384, bl, bh, dst, o);
}

// 128x64 tile GEMM; ring-3 staging; raw s_barrier + vmcnt(6) (never 0 mid-loop)
template <int AX0, int AX1, int AX2>
__device__ __forceinline__ void run_gemm_g(const char* A0, int n0, const char* A1, int n1,
                                           const char* A2, const char* Bs, int S, char* smem,
                                           int tid, int wm, int wn, int lane,
                                           f32x4 (&acc)[4][2]) {
  const int o = tid * 16;
  stg_disp_g<AX0, AX1, AX2>(0, A0, n0, A1, n1, A2, Bs, smem, o);
  if (S > 1) stg_disp_g<AX0, AX1, AX2>(1, A0, n0, A1, n1, A2, Bs, smem + SLOT_G, o);
  const int ab = wm * 4096 + lane * 16;
  const int bb = 16384 + wn * 2048 + lane * 16;
  for (int s = 0; s < S; ++s) {
    if (s + 1 < S)
      __builtin_amdgcn_s_waitcnt(0x0F76);  // vmcnt(6)
    else
      __builtin_amdgcn_s_waitcnt(0x0F70);  // vmcnt(0) tail
    __builtin_amdgcn_s_barrier();
    char* sb = smem + (s % 3) * SLOT_G;
    if (s + 2 < S)
      stg_disp_g<AX0, AX1, AX2>(s + 2, A0, n0, A1, n1, A2, Bs, smem + ((s + 2) % 3) * SLOT_G, o);
#pragma unroll
    for (int c = 0; c < 2; ++c) {
      const char* ap = sb + c * 8192 + ab;
      const char* bp = sb + c * 4096 + bb;
      bf16x8 Af0 = *(const bf16x8*)(ap);
      bf16x8 Af1 = *(const bf16x8*)(ap + 1024);
      bf16x8 Af2 = *(const bf16x8*)(ap + 2048);
      bf16x8 Af3 = *(const bf16x8*)(ap + 3072);
      bf16x8 Bf0 = *(const bf16x8*)(bp);
      bf16x8 Bf1 = *(const bf16x8*)(bp + 1024);
      acc[0][0] = mfma16(Af0, Bf0, acc[0][0]);
      acc[0][1] = mfma16(Af0, Bf1, acc[0][1]);
      acc[1][0] = mfma16(Af1, Bf0, acc[1][0]);
      acc[1][1] = mfma16(Af1, Bf1, acc[1][1]);
      acc[2][0] = mfma16(Af2, Bf0, acc[2][0]);
      acc[2][1] = mfma16(Af2, Bf1, acc[2][1]);
      acc[3][0] = mfma16(Af3, Bf0, acc[3][0]);
      acc[3][1] = mfma16(Af3, Bf1, acc[3][1]);
    }
  }
  __syncthreads();
}

// 128x128 tile GEMM (logits): wave = 64x64 (acc[4][4]); wn picks Blo/Bhi
template <int AX0, int AX1>
__device__ __forceinline__ void run_gemm_l(const char* A0, int n0, const char* A1,
                                           const char* Blo, const char* Bhi, int S, char* smem,
                                           int tid, int wm, int wn, int lane,
                                           f32x4 (&acc)[4][4]) {
  const int o = tid * 16;
  stg_disp_l<AX0, AX1>(0, A0, n0, A1, Blo, Bhi, smem, o);
  stg_disp_l<AX0, AX1>(1, A0, n0, A1, Blo, Bhi, smem + SLOT_L, o);
  const int ab = wm * 4096 + lane * 16;
  const int bb = 16384 + wn * 8192 + lane * 16;
  for (int s = 0; s < S; ++s) {
    if (s + 1 < S)
      __builtin_amdgcn_s_waitcnt(0x0F78);  // vmcnt(8)
    else
      __builtin_amdgcn_s_waitcnt(0x0F70);
    __builtin_amdgcn_s_barrier();
    char* sb = smem + (s % 3) * SLOT_L;
    if (s + 2 < S)
      stg_disp_l<AX0, AX1>(s + 2, A0, n0, A1, Blo, Bhi, smem + ((s + 2) % 3) * SLOT_L, o);
#pragma unroll
    for (int c = 0; c < 2; ++c) {
      const char* ap = sb + c * 8192 + ab;
      const char* bp = sb + c * 4096 + bb;
      bf16x8 Af[4], Bf[4];
#pragma unroll
      for (int m = 0; m < 4; ++m) Af[m] = *(const bf16x8*)(ap + m * 1024);
#pragma unroll
      for (int n = 0; n < 4; ++n) Bf[n] = *(const bf16x8*)(bp + n * 1024);
#pragma unroll
      for (int m = 0; m < 4; ++m)
#pragma unroll
        for (int n = 0; n < 4; ++n) acc[m][n] = mfma16(Af[m], Bf[n], acc[m][n]);
    }
  }
  __syncthreads();
}

// C/D layout: col = lane&15, row = (lane>>4)*4 + reg
__device__ __forceinline__ void store_lds_tile(float* lds, f32x4 (&acc)[4][2], int wm, int wn,
                                               int lane) {
  const int l15 = lane & 15, lq = lane >> 4;
#pragma unroll
  for (int m = 0; m < 4; ++m)
#pragma unroll
    for (int n = 0; n < 2; ++n)
#pragma unroll
      for (int r = 0; r < 4; ++r)
        lds[(wm * 64 + m * 16 + lq * 4 + r) * 68 + (wn * 32 + n * 16 + l15)] = acc[m][n][r];
}
__device__ __forceinline__ void store_lds_tile128(float* lds, f32x4 (&acc)[4][4], int wm, int wn,
                                                  int lane) {
  const int l15 = lane & 15, lq = lane >> 4;
#pragma unroll
  for (int m = 0; m < 4; ++m)
#pragma unroll
    for (int n = 0; n < 4; ++n)
#pragma unroll
      for (int r = 0; r < 4; ++r)
        lds[(wm * 64 + m * 16 + lq * 4 + r) * 132 + (wn * 64 + n * 16 + l15)] = acc[m][n][r];
}

// fence-free hierarchical grid barrier. Ordering: __syncthreads() emits
// s_waitcnt vmcnt(0) per wave (drains this wave's sc0sc1 data stores to the
// coherence point) BEFORE the relaxed flag store. Consumers' mutable reads
// are sc0sc1 (bypass L1/L2), so no invalidate is needed.
__device__ __forceinline__ void grid_barrier4(uint* flags, uint* epoch, uint ph, bool isAgg) {
  __syncthreads();
  if (threadIdx.x == 0) ast32(&flags[blockIdx.x], ph);
  if (isAgg) {
    uint v = ald32(&flags[threadIdx.x]);
    while (v < ph) {
      __builtin_amdgcn_s_sleep(1);
      v = ald32(&flags[threadIdx.x]);
    }
    __syncthreads();
    if (threadIdx.x == 0) ast32(epoch, ph);
  } else if (threadIdx.x == 0) {
    uint v = ald32(epoch);
    while (v < ph) {
      __builtin_amdgcn_s_sleep(1);
      v = ald32(epoch);
    }
  }
  __syncthreads();
}

// LSTM gate pointwise; tile [128 b][16 d x 4 g] f32; C in registers; paired-d
// so h/hs go out as packed-uint coherent stores.
template <bool WHS>
__device__ __forceinline__ void gates_pw4(const float* tile, int tid, int b0, int d0,
                                          const float* __restrict__ bg, float (&cp)[8],
                                          ushort* __restrict__ hw, const ushort* __restrict__ h0r,
                                          ushort* __restrict__ hs) {
#pragma unroll
  for (int jj = 0; jj < 4; ++jj) {
    const int pi = tid + jj * 256;  // 0..1023 pair index
    const int bl = pi >> 3, e = pi & 7;
    const f32x4 g0 = ((const f32x4*)tile)[bl * 17 + 2 * e];
    const f32x4 g1 = ((const f32x4*)tile)[bl * 17 + 2 * e + 1];
    const int d = d0 + 2 * e, b = b0 + bl;
    float h2[2];
#pragma unroll
    for (int u = 0; u < 2; ++u) {
      const f32x4 g = u ? g1 : g0;
      const int dd = d + u;
      const float ii = sigm(g[0] + bg[dd]);
      const float ff = sigm(g[1] + bg[512 + dd]);
      const float oo = sigm(g[2] + bg[1024 + dd]);
      const float cn = tanh_f(g[3] + bg[1536 + dd]);
      const float c = ff * cp[jj * 2 + u] + ii * cn;
      cp[jj * 2 + u] = c;
      h2[u] = oo * tanh_f(c);
    }
    const long ft = fta(b, d, 16);  // even -> 4B aligned in ushort units
    ast32((uint*)(hw + ft), (uint)f2bf(h2[0]) | ((uint)f2bf(h2[1]) << 16));
    if (WHS) {
      const uint h0p = ald32((const uint*)(h0r + ft));
      const float s0 = h2[0] + bf2f((ushort)(h0p & 0xffffu));
      const float s1 = h2[1] + bf2f((ushort)(h0p >> 16));
      ast32((uint*)(hs + ft), (uint)f2bf(s0) | ((uint)f2bf(s1) << 16));
    }
  }
}

__device__ __forceinline__ float combine_row4(const float* __restrict__ MBc,
                                              const float* __restrict__ SBc,
                                              const float* __restrict__ TGTc, int r, int lane) {
  float M = lane < 40 ? aldf(&MBc[r * 40 + lane]) : -3.0e38f;
  float S = lane < 40 ? aldf(&SBc[r * 40 + lane]) : 0.f;
#pragma unroll
  for (int off = 32; off > 0; off >>= 1) {
    const float Mo = __shfl_xor(M, off, 64);
    const float So = __shfl_xor(S, off, 64);
    const float Mn = fmaxf(M, Mo);
    S = S * __expf(M - Mn) + So * __expf(Mo - Mn);
    M = Mn;
  }
  return aldf(&TGTc[r]) - (M + __logf(S));
}

// ---------------------------------------------------------------------------
__device__ __forceinline__ void cv8(ushort8v& o, const float* s) {
  const f32x4 a = *(const f32x4*)s, b = *(const f32x4*)(s + 4);
#pragma unroll
  for (int j = 0; j < 4; ++j) o[j] = f2bf(a[j]);
#pragma unroll
  for (int j = 0; j < 4; ++j) o[4 + j] = f2bf(b[j]);
}
__device__ __forceinline__ void bft8(ushort* dst, int col, int kg, int KC, const float* src) {
  ushort8v o;
  cv8(o, src);
  *(ushort8v*)(dst + ((long)((col >> 6) * KC + (kg >> 2)) << 11) +
               (((((col >> 4) & 3) << 2) + (kg & 3)) << 7) + ((col & 15) << 3)) = o;
}
__device__ __forceinline__ void bft8z(ushort* dst, int col, int kg, int KC) {
  ushort8v o = (ushort8v)0;
  *(ushort8v*)(dst + ((long)((col >> 6) * KC + (kg >> 2)) << 11) +
               (((((col >> 4) & 3) << 2) + (kg & 3)) << 7) + ((col & 15) << 3)) = o;
}
__device__ __forceinline__ void aft8(ushort* dst, int b, int kg, int KC, const float* src) {
  ushort8v o;
  cv8(o, src);
  *(ushort8v*)(dst + ((long)(((b >> 7) & 1) * KC + (kg >> 2)) << 12) +
               (((((b >> 4) & 7) << 2) + (kg & 3)) << 7) + ((b & 15) << 3)) = o;
}

__global__ void __launch_bounds__(256) prep_kernel(
    const float* __restrict__ Wg0, const float* __restrict__ Wg1, const float* __restrict__ Wout,
    const float* __restrict__ emb, const float* __restrict__ z, const int* __restrict__ x,
    const float* __restrict__ tw1, const float* __restrict__ tw2, unsigned char* __restrict__ ws) {
  ushort* W0 = (ushort*)(ws + OFF_W0);
  ushort* W1 = (ushort*)(ws + OFF_W1);
  ushort* WO = (ushort*)(ws + OFF_WO);
  ushort* EF = (ushort*)(ws + OFF_EFT);
  ushort* ZF = (ushort*)(ws + OFF_ZFT);
  ushort* T1 = (ushort*)(ws + OFF_TW1);
  ushort* T2 = (ushort*)(ws + OFF_TW2);
  const long N0 = 294912, N1 = 262144, N2 = 409600, N3 = 655360, N4 = 4096, N5 = 65536,
             N6 = 524288;
  const long total = N0 + N1 + N2 + N3 + N4 + N5 + N6;
  for (long idx = (long)blockIdx.x * 256 + threadIdx.x; idx < total;
       idx += (long)gridDim.x * 256) {
    long j = idx;
    if (j < N0) {  // W0: gate-interleaved col r=d*4+g
      const int col = (int)(j / 144), kg = (int)(j - (long)col * 144);
      bft8(W0, col, kg, 36, Wg0 + (long)((col & 3) * 512 + (col >> 2)) * 1152 + kg * 8);
    } else if ((j -= N0) < N1) {
      const int col = (int)(j >> 7), kg = (int)(j & 127);
      bft8(W1, col, kg, 32, Wg1 + (long)((col & 3) * 512 + (col >> 2)) * 1024 + kg * 8);
    } else if ((j -= N1) < N2) {
      const int col = (int)(j / 80), kg = (int)(j - (long)col * 80);
      if (col < 5000)
        bft8(WO, col, kg, 20, Wout + (long)col * 640 + kg * 8);
      else
        bft8z(WO, col, kg, 20);
    } else if ((j -= N2) < N3) {  // emb gather, all t
      const int t = (int)(j >> 14), r = (int)(j & 16383);
      const int b = r >> 6, kg = r & 63;
      aft8(EF + (long)t * 131072, b, kg, 16, emb + (long)x[b * 40 + t] * 512 + kg * 8);
    } else if ((j -= N3) < N4) {
      const int b = (int)(j >> 4), kg = (int)(j & 15);
      aft8(ZF, b, kg, 4, z + b * 128 + kg * 8);
    } else if ((j -= N4) < N5) {
      const int col = (int)(j >> 4), kg = (int)(j & 15);
      bft8(T1, col, kg, 4, tw1 + (long)(col >> 11) * 262144 + (long)(col & 2047) * 128 + kg * 8);
    } else {
      j -= N5;
      const int col = (int)(j >> 8), kg = (int)(j & 255);
      bft8(T2, col, kg, 64, tw2 + (long)(col >> 10) * 2097152 + (long)(col & 1023) * 2048 + kg * 8);
    }
  }
}

// ---------------------------------------------------------------------------
__global__ void __launch_bounds__(256) decoder_main(
    const int* __restrict__ x, const float* __restrict__ bg0, const float* __restrict__ bg1,
    const float* __restrict__ bout, const float* __restrict__ tb1, const float* __restrict__ tb2,
    unsigned char* __restrict__ ws, float* __restrict__ out) {
  __shared__ __align__(16) char smem[98304];  // logits ring 3x32KB; others smaller

  uint* flags = (uint*)(ws + OFF_FLAGS);
  uint* epoch = (uint*)(ws + OFF_FLAGS + 1024);
  const char* cW0 = (const char*)(ws + OFF_W0);
  const char* cW1 = (const char*)(ws + OFF_W1);
  const char* cWO = (const char*)(ws + OFF_WO);
  const char* cEF = (const char*)(ws + OFF_EFT);
  const char* cZF = (const char*)(ws + OFF_ZFT);
  const char* cT1 = (const char*)(ws + OFF_TW1);
  const char* cT2 = (const char*)(ws + OFF_TW2);
  char* cGB = (char*)(ws + OFF_GB);
  char* cH0 = (char*)(ws + OFF_H0);
  char* cH1 = (char*)(ws + OFF_H1);
  char* cHS = (char*)(ws + OFF_HS);
  float* C0f = (float*)(ws + OFF_C0);
  float* C1f = (float*)(ws + OFF_C1);
  float* MBf = (float*)(ws + OFF_MB);
  float* SBf = (float*)(ws + OFF_SB);
  float* TGTf = (float*)(ws + OFF_TGT);

  const int bid = blockIdx.x;
  const int tid = threadIdx.x;
  const int lane = tid & 63;
  const int w = tid >> 6;
  const int wm = w & 1, wn = w >> 1;
  const int xcd = bid & 7;          // round-robin block->XCD heuristic (perf only)
  const int slot = bid >> 3;        // 0..31 within XCD
  const bool isAgg = (bid == 240);  // idle class

  uint ph = 0;
  float cpriv[8];
  float accO0 = 0.f, accO1 = 0.f;

  // ======== init1: relu(z @ tw1^T + tb1) -> GB (coherent stores) ========
  if (slot < 16) {
    const int i_mt = slot & 1, i_ng = xcd * 8 + (slot >> 1);
    f32x4 acc[4][2];
#pragma unroll
    for (int m = 0; m < 4; ++m)
#pragma unroll
      for (int n = 0; n < 2; ++n) acc[m][n] = (f32x4){0.f, 0.f, 0.f, 0.f};
    run_gemm_g<0, 0, 0>(cZF + (long)i_mt * 32768, 2, nullptr, 0, nullptr,
                        cT1 + (long)i_ng * 16384, 2, smem, tid, wm, wn, lane, acc);
    store_lds_tile((float*)smem, acc, wm, wn, lane);
    __syncthreads();
    const int b0i = i_mt * 128, n0i = i_ng * 64;
    ushort* GBu = (ushort*)cGB;
    for (int i = tid; i < 2048; i += 256) {
      const int bl = i >> 4, q = i & 15;
      const f32x4 v = ((const f32x4*)smem)[bl * 17 + q];
      const int cb = n0i + q * 4;
      const int l = cb >> 11, rr = cb & 2047;
      u64 pk = 0;
#pragma unroll
      for (int cc = 0; cc < 4; ++cc)
        pk |= (u64)f2bf(fmaxf(v[cc] + tb1[cb + cc], 0.f)) << (cc * 16);
      ast64((u64*)(GBu + (long)l * 524288 + fta(b0i + bl, rr, 64)), pk);
    }
  }
  grid_barrier4(flags, epoch, ++ph, isAgg);

  // ======== init2: tanh(GB @ tw2^T + tb2) -> (h parity1, C), coherent ========
  if (slot < 8) {
    const int i_mt = slot & 1, i_ng = xcd * 4 + (slot >> 1);
    const int l = i_ng >> 4;
    f32x4 acc[4][2];
#pragma unroll
    for (int m = 0; m < 4; ++m)
#pragma unroll
      for (int n = 0; n < 2; ++n) acc[m][n] = (f32x4){0.f, 0.f, 0.f, 0.f};
    run_gemm_g<AUXC, 0, 0>(cGB + (long)l * 1048576 + (long)i_mt * 524288, 32, nullptr, 0, nullptr,
                           cT2 + (long)i_ng * 262144, 32, smem, tid, wm, wn, lane, acc);
    store_lds_tile((float*)smem, acc, wm, wn, lane);
    __syncthreads();
    const int b0i = i_mt * 128, n0i = i_ng * 64;
    for (int i = tid; i < 2048; i += 256) {
      const int bl = i >> 4, q = i & 15;
      const f32x4 v = ((const f32x4*)smem)[bl * 17 + q];
      const int cb = n0i + q * 4;
      const int ll = cb >> 10, rr = cb & 1023;
      const int b = b0i + bl;
      if (rr < 512) {  // initial h at parity 1
        u64 pk = 0;
#pragma unroll
        for (int cc = 0; cc < 4; ++cc) pk |= (u64)f2bf(tanh_f(v[cc] + tb2[cb + cc])) << (cc * 16);
        ast64((u64*)((ushort*)((ll ? cH1 : cH0) + HPAR) + fta(b, rr, 16)), pk);
      } else {
        float* Cf = (ll ? C1f : C0f) + b * 512 + (rr - 512);
#pragma unroll
        for (int cc = 0; cc < 4; ++cc) astf(Cf + cc, tanh_f(v[cc] + tb2[cb + cc]));
      }
    }
  }
  grid_barrier4(flags, epoch, ++ph, isAgg);

  // block-persistent roles + C tile -> registers (coherent loads)
  const int mt = slot & 1;
  const int gng = xcd * 4 + ((slot & 7) >> 1);  // for G0/G1
  if (slot < 16) {
    const float* Cf = (slot < 8) ? C0f : C1f;
#pragma unroll
    for (int jj = 0; jj < 4; ++jj) {
      const int pi = tid + jj * 256, bl = pi >> 3, e = pi & 7;
      const int b = mt * 128 + bl, d = gng * 16 + 2 * e;
      cpriv[jj * 2 + 0] = aldf(&Cf[b * 512 + d]);
      cpriv[jj * 2 + 1] = aldf(&Cf[b * 512 + d + 1]);
    }
  }

  // ======== 42 pipelined phases ========
  for (int k = 0; k < 42; ++k) {
    if (slot < 8) {  // ---- G0: L0 gates, t = k ----
      if (k <= 39) {
        f32x4 acc[4][2];
#pragma unroll
        for (int m = 0; m < 4; ++m)
#pragma unroll
          for (int n = 0; n < 2; ++n) acc[m][n] = (f32x4){0.f, 0.f, 0.f, 0.f};
        run_gemm_g<AUXC, 0, 0>(cH0 + (long)((k - 1) & 1) * HPAR + (long)mt * HMT, 8,
                               cEF + (long)k * HPAR + (long)mt * HMT, 8, cZF + (long)mt * 32768,
                               cW0 + (long)gng * 147456, 18, smem, tid, wm, wn, lane, acc);
        store_lds_tile((float*)smem, acc, wm, wn, lane);
        __syncthreads();
        gates_pw4<false>((const float*)smem, tid, mt * 128, gng * 16, bg0, cpriv,
                         (ushort*)(cH0 + (long)(k & 1) * HPAR), nullptr, nullptr);
      }
    } else if (slot < 16) {  // ---- G1: L1 gates, t = k-1 (+HS) ----
      if (k >= 1 && k <= 40) {
        f32x4 acc[4][2];
#pragma unroll
        for (int m = 0; m < 4; ++m)
#pragma unroll
          for (int n = 0; n < 2; ++n) acc[m][n] = (f32x4){0.f, 0.f, 0.f, 0.f};
        run_gemm_g<AUXC, AUXC, 0>(cH1 + (long)(k & 1) * HPAR + (long)mt * HMT, 8,
                                  cH0 + (long)((k - 1) & 1) * HPAR + (long)mt * HMT, 8, nullptr,
                                  cW1 + (long)gng * 131072, 16, smem, tid, wm, wn, lane, acc);
        store_lds_tile((float*)smem, acc, wm, wn, lane);
        __syncthreads();
        gates_pw4<true>((const float*)smem, tid, mt * 128, gng * 16, bg1, cpriv,
                        (ushort*)(cH1 + (long)((k - 1) & 1) * HPAR),
                        (const ushort*)(cH0 + (long)((k - 1) & 1) * HPAR),
                        (ushort*)(cHS + (long)((k - 1) & 1) * HPAR));
      }
    } else if (slot < 26) {  // ---- logits, t' = k-2, target x[.,k-1] ----
      if (k >= 2 && k <= 40) {
        const int ls = slot - 16, lmt = ls & 1, lng = xcd * 5 + (ls >> 1);
        f32x4 acc[4][4];
#pragma unroll
        for (int m = 0; m < 4; ++m)
#pragma unroll
          for (int n = 0; n < 4; ++n) acc[m][n] = (f32x4){0.f, 0.f, 0.f, 0.f};
        run_gemm_l<AUXC, 0>(cHS + (long)(k & 1) * HPAR + (long)lmt * HMT, 8,
                            cZF + (long)lmt * 32768, cWO + (long)(2 * lng) * 81920,
                            cWO + (long)(2 * lng + 1) * 81920, 10, smem, tid, wm, wn, lane, acc);
        store_lds_tile128((float*)smem, acc, wm, wn, lane);
        __syncthreads();
        const int row = tid >> 1, half = tid & 1, b = lmt * 128 + row;
        const int n0 = lng * 128 + half * 64;
        const int xt = x[b * 40 + (k - 1)];
        const float* rowp = (const float*)smem + row * 132 + half * 64;
        float mx = -3.0e38f, tv = 0.f;
        for (int j = 0; j < 64; j += 4) {
          const f32x4 v = *(const f32x4*)(rowp + j);
#pragma unroll
          for (int cc = 0; cc < 4; ++cc) {
            const int col = n0 + j + cc;
            if (col < 5000) {
              const float val = v[cc] + bout[col];
              mx = fmaxf(mx, val);
              if (col == xt) tv = val;
            }
          }
        }
        float sa = 0.f;
        for (int j = 0; j < 64; j += 4) {
          const f32x4 v = *(const f32x4*)(rowp + j);
#pragma unroll
          for (int cc = 0; cc < 4; ++cc) {
            const int col = n0 + j + cc;
            if (col < 5000) sa += __expf(v[cc] + bout[col] - mx);
          }
        }
        const float mo = __shfl_xor(mx, 1, 64), so = __shfl_xor(sa, 1, 64),
                    to = __shfl_xor(tv, 1, 64);
        const float Mn = fmaxf(mx, mo);
        const float Sm = sa * __expf(mx - Mn) + so * __expf(mo - Mn);
        const int par = k & 1;
        if (half == 0) {
          astf(&MBf[par * 10240 + b * 40 + lng], Mn);
          astf(&SBf[par * 10240 + b * 40 + lng], Sm);
          if (xt >= lng * 128 && xt < lng * 128 + 128) astf(&TGTf[par * 256 + b], tv + to);
        }
      }
    } else if (slot < 30) {  // ---- combine, logits of phase k-1 ----
      if (k >= 3 && k <= 41) {
        const int par = (k - 1) & 1;
        const int r0 = (xcd * 4 + (slot - 26)) * 8 + w * 2;
        accO0 += combine_row4(MBf + par * 10240, SBf + par * 10240, TGTf + par * 256, r0, lane);
        accO1 +=
            combine_row4(MBf + par * 10240, SBf + par * 10240, TGTf + par * 256, r0 + 1, lane);
      }
    }
    grid_barrier4(flags, epoch, ++ph, isAgg);
  }

  if (slot >= 26 && slot < 30 && lane == 0) {
    const int r0 = (xcd * 4 + (slot - 26)) * 8 + w * 2;
    out[r0] = accO0;
    out[r0 + 1] = accO1;
  }
}

// ---------------------------------------------------------------------------
extern "C" void kernel_launch(void* const* d_in, const int* in_sizes, int n_in, void* d_out,
                              int out_size, void* d_ws, size_t ws_size, hipStream_t stream) {
  const float* z = (const float*)d_in[0];
  const int* x = (const int*)d_in[1];
  const float* emb = (const float*)d_in[2];
  const float* Wg0 = (const float*)d_in[3];
  const float* bg0 = (const float*)d_in[4];
  const float* Wg1 = (const float*)d_in[5];
  const float* bg1 = (const float*)d_in[6];
  const float* Wout = (const float*)d_in[7];
  const float* bout = (const float*)d_in[8];
  const float* tw1 = (const float*)d_in[9];
  const float* tb1 = (const float*)d_in[10];
  const float* tw2 = (const float*)d_in[11];
  const float* tb2 = (const float*)d_in[12];
  unsigned char* ws = (unsigned char*)d_ws;
  float* out = (float*)d_out;

  hipMemsetAsync(ws, 0, 4096, stream);  // flags + epoch
  prep_kernel<<<2048, 256, 0, stream>>>(Wg0, Wg1, Wout, emb, z, x, tw1, tw2, ws);
  decoder_main<<<256, 256, 0, stream>>>(x, bg0, bg1, bout, tb1, tb2, ws, out);
}